// Round 2
// baseline (629.565 us; speedup 1.0000x reference)
//
#include <hip/hip_runtime.h>
#include <hip/hip_bf16.h>

// Problem constants (fixed by the reference)
#define NN 32768      // nodes
#define GG 64         // graphs
#define NPG 512       // nodes per graph
#define HD 128        // feature/hidden width
#define RSQRT_H 0.08838834764831845f  // 1/sqrt(128)

// ---------------------------------------------------------------- init / CSR
__global__ void k_init(int* __restrict__ deg, int* __restrict__ cursor,
                       float* __restrict__ wcol) {
    int i = blockIdx.x * 256 + threadIdx.x;   // 32768 total; wcol is 64*512=32768
    deg[i] = 0; cursor[i] = 0; wcol[i] = 0.f;
}

__global__ void k_deg(const int* __restrict__ dst, int* __restrict__ deg, int E) {
    int e = blockIdx.x * 256 + threadIdx.x;
    if (e < E) atomicAdd(&deg[dst[e]], 1);
}

__global__ void k_scan(const int* __restrict__ deg, int* __restrict__ rowoff) {
    __shared__ int buf[256];
    __shared__ int carry;
    int t = threadIdx.x;
    if (t == 0) carry = 0;
    __syncthreads();
    for (int base = 0; base < NN; base += 256) {
        int v = deg[base + t];
        buf[t] = v;
        __syncthreads();
        for (int off = 1; off < 256; off <<= 1) {
            int add = (t >= off) ? buf[t - off] : 0;
            __syncthreads();
            buf[t] += add;
            __syncthreads();
        }
        int incl = buf[t];
        rowoff[base + t] = carry + incl - v;   // exclusive
        __syncthreads();
        if (t == 255) carry += incl;
        __syncthreads();
    }
    if (t == 0) rowoff[NN] = carry;
}

__global__ void k_dinv(const int* __restrict__ deg, float* __restrict__ dinv) {
    int i = blockIdx.x * 256 + threadIdx.x;
    dinv[i] = rsqrtf((float)(deg[i] + 1));     // +1 self-loop; always >= 1
}

__global__ void k_csr(const int* __restrict__ src, const int* __restrict__ dst,
                      const int* __restrict__ rowoff, int* __restrict__ cursor,
                      int* __restrict__ csr, int E) {
    int e = blockIdx.x * 256 + threadIdx.x;
    if (e < E) {
        int d = dst[e];
        int pos = rowoff[d] + atomicAdd(&cursor[d], 1);
        csr[pos] = src[e];
    }
}

// ---------------------------------------------------------------- GEMM [M,128]@[128,128]
// 64x64 tile, 256 threads, 4x4 micro-tile. A row-major in LDS (pad 132),
// W k-major (pad 68). All hot-loop LDS reads are <=2-way conflicts (free).
#define FMA_ROW(r, av, wv) \
    acc[r][0] += (av)*(wv).x; acc[r][1] += (av)*(wv).y; \
    acc[r][2] += (av)*(wv).z; acc[r][3] += (av)*(wv).w;

template<int TRANS_OUT, int BIAS>
__global__ __launch_bounds__(256) void k_gemm(
    const float* __restrict__ A, const float* __restrict__ W,
    const float* __restrict__ bias, float* __restrict__ out, int M)
{
    __shared__ float Al[64][132];
    __shared__ float Wt[128][68];
    int t = threadIdx.x;
    int row0 = blockIdx.x * 64;
    int col0 = blockIdx.y * 64;

    const float4* A4 = (const float4*)(A + (size_t)row0 * HD);
#pragma unroll
    for (int i = 0; i < 8; ++i) {
        int idx = t + 256 * i;          // 2048 float4 = 64 rows x 32 kquads
        int r = idx >> 5, kq = idx & 31;
        *(float4*)&Al[r][kq * 4] = A4[idx];
    }
    const float4* W4 = (const float4*)W;
#pragma unroll
    for (int i = 0; i < 8; ++i) {
        int idx = t + 256 * i;          // 2048 float4 = 128 k x 16 colquads
        int k = idx >> 4, cq = idx & 15;
        *(float4*)&Wt[k][cq * 4] = W4[k * 32 + (col0 >> 2) + cq];
    }
    __syncthreads();

    int cg = t & 15, rg = t >> 4;
    float acc[4][4] = {{0.f}};
#pragma unroll 2
    for (int kk = 0; kk < 128; kk += 4) {
        float4 a0 = *(const float4*)&Al[rg * 4 + 0][kk];
        float4 a1 = *(const float4*)&Al[rg * 4 + 1][kk];
        float4 a2 = *(const float4*)&Al[rg * 4 + 2][kk];
        float4 a3 = *(const float4*)&Al[rg * 4 + 3][kk];
        float4 w0 = *(const float4*)&Wt[kk + 0][cg * 4];
        float4 w1 = *(const float4*)&Wt[kk + 1][cg * 4];
        float4 w2 = *(const float4*)&Wt[kk + 2][cg * 4];
        float4 w3 = *(const float4*)&Wt[kk + 3][cg * 4];
        FMA_ROW(0, a0.x, w0) FMA_ROW(0, a0.y, w1) FMA_ROW(0, a0.z, w2) FMA_ROW(0, a0.w, w3)
        FMA_ROW(1, a1.x, w0) FMA_ROW(1, a1.y, w1) FMA_ROW(1, a1.z, w2) FMA_ROW(1, a1.w, w3)
        FMA_ROW(2, a2.x, w0) FMA_ROW(2, a2.y, w1) FMA_ROW(2, a2.z, w2) FMA_ROW(2, a2.w, w3)
        FMA_ROW(3, a3.x, w0) FMA_ROW(3, a3.y, w1) FMA_ROW(3, a3.z, w2) FMA_ROW(3, a3.w, w3)
    }

    if (!TRANS_OUT) {
#pragma unroll
        for (int r = 0; r < 4; ++r) {
            int row = row0 + rg * 4 + r;
            int c = col0 + cg * 4;
            float4 o = make_float4(acc[r][0], acc[r][1], acc[r][2], acc[r][3]);
            if (BIAS) { o.x += bias[c]; o.y += bias[c+1]; o.z += bias[c+2]; o.w += bias[c+3]; }
            *(float4*)&out[(size_t)row * HD + c] = o;
        }
    } else {
        // restage through LDS so the [col][row] global writes are coalesced
        __syncthreads();
        float* Sl = &Al[0][0];              // stride 68, 64x64 tile
#pragma unroll
        for (int r = 0; r < 4; ++r) {
            float4 o = make_float4(acc[r][0], acc[r][1], acc[r][2], acc[r][3]);
            *(float4*)&Sl[(rg * 4 + r) * 68 + cg * 4] = o;
        }
        __syncthreads();
#pragma unroll
        for (int i = 0; i < 4; ++i) {
            int idx = t + 256 * i;          // 1024 float4 = 64 cols x 16 rowquads
            int c = idx >> 4, rq = idx & 15;
            float4 o = make_float4(Sl[(rq * 4 + 0) * 68 + c], Sl[(rq * 4 + 1) * 68 + c],
                                   Sl[(rq * 4 + 2) * 68 + c], Sl[(rq * 4 + 3) * 68 + c]);
            if (BIAS) { float b = bias[col0 + c]; o.x += b; o.y += b; o.z += b; o.w += b; }
            *(float4*)&out[(size_t)(col0 + c) * M + row0 + rq * 4] = o;
        }
    }
}

// ---------------------------------------------------------------- aggregation
// one block (128 threads) per node: acc = self + sum over in-edges, then +b, relu
__global__ __launch_bounds__(128) void k_agg(
    const float* __restrict__ tmat, const float* __restrict__ dinv,
    const int* __restrict__ rowoff, const int* __restrict__ csr,
    const float* __restrict__ bias, float* __restrict__ hout)
{
    int i = blockIdx.x, t = threadIdx.x;
    float di = dinv[i];
    float acc = tmat[(size_t)i * HD + t] * di * di;     // self-loop
    int e0 = rowoff[i], e1 = rowoff[i + 1];
    for (int e = e0; e < e1; ++e) {
        int s = csr[e];
        acc += tmat[(size_t)s * HD + t] * (dinv[s] * di);
    }
    hout[(size_t)i * HD + t] = fmaxf(acc + bias[t], 0.f);
}

// ---------------------------------------------------------------- attention
// Per (graph, 64-row q-tile): pass A = online (max,sumexp) per row over all 512
// keys; pass B = recompute S, accumulate attn column sums into wl -> global w.
__global__ __launch_bounds__(256) void k_attn(
    const float* __restrict__ q,    // [N][128]
    const float* __restrict__ kT,   // [128][N]
    float* __restrict__ wsum)       // [64][512]
{
    __shared__ float Ql[64][132];
    __shared__ float Kt[128][68];
    __shared__ float wl[512];
    int t = threadIdx.x;
    int g = blockIdx.x >> 3;
    int qt = blockIdx.x & 7;
    int qrow0 = g * NPG + qt * 64;

    wl[t] = 0.f; wl[t + 256] = 0.f;
    const float4* q4 = (const float4*)(q + (size_t)qrow0 * HD);
#pragma unroll
    for (int i = 0; i < 8; ++i) {
        int idx = t + 256 * i;
        int r = idx >> 5, kq = idx & 31;
        *(float4*)&Ql[r][kq * 4] = q4[idx];
    }
    int cg = t & 15, rg = t >> 4;
    float mrow[4], lrow[4];
#pragma unroll
    for (int r = 0; r < 4; ++r) { mrow[r] = -3.0e38f; lrow[r] = 0.f; }

    // ---------------- pass A: row max + sumexp (online)
    for (int mt = 0; mt < 8; ++mt) {
        __syncthreads();
        int node0 = g * NPG + mt * 64;
#pragma unroll
        for (int i = 0; i < 8; ++i) {
            int idx = t + 256 * i;      // 2048 float4 = 128 d x 16 colquads
            int d = idx >> 4, cq = idx & 15;
            *(float4*)&Kt[d][cq * 4] =
                *(const float4*)&kT[(size_t)d * NN + node0 + cq * 4];
        }
        __syncthreads();
        float s[4][4] = {{0.f}};
#pragma unroll 2
        for (int kk = 0; kk < 128; kk += 4) {
            float4 a0 = *(const float4*)&Ql[rg * 4 + 0][kk];
            float4 a1 = *(const float4*)&Ql[rg * 4 + 1][kk];
            float4 a2 = *(const float4*)&Ql[rg * 4 + 2][kk];
            float4 a3 = *(const float4*)&Ql[rg * 4 + 3][kk];
            float4 w0 = *(const float4*)&Kt[kk + 0][cg * 4];
            float4 w1 = *(const float4*)&Kt[kk + 1][cg * 4];
            float4 w2 = *(const float4*)&Kt[kk + 2][cg * 4];
            float4 w3 = *(const float4*)&Kt[kk + 3][cg * 4];
            s[0][0]+=a0.x*w0.x; s[0][1]+=a0.x*w0.y; s[0][2]+=a0.x*w0.z; s[0][3]+=a0.x*w0.w;
            s[0][0]+=a0.y*w1.x; s[0][1]+=a0.y*w1.y; s[0][2]+=a0.y*w1.z; s[0][3]+=a0.y*w1.w;
            s[0][0]+=a0.z*w2.x; s[0][1]+=a0.z*w2.y; s[0][2]+=a0.z*w2.z; s[0][3]+=a0.z*w2.w;
            s[0][0]+=a0.w*w3.x; s[0][1]+=a0.w*w3.y; s[0][2]+=a0.w*w3.z; s[0][3]+=a0.w*w3.w;
            s[1][0]+=a1.x*w0.x; s[1][1]+=a1.x*w0.y; s[1][2]+=a1.x*w0.z; s[1][3]+=a1.x*w0.w;
            s[1][0]+=a1.y*w1.x; s[1][1]+=a1.y*w1.y; s[1][2]+=a1.y*w1.z; s[1][3]+=a1.y*w1.w;
            s[1][0]+=a1.z*w2.x; s[1][1]+=a1.z*w2.y; s[1][2]+=a1.z*w2.z; s[1][3]+=a1.z*w2.w;
            s[1][0]+=a1.w*w3.x; s[1][1]+=a1.w*w3.y; s[1][2]+=a1.w*w3.z; s[1][3]+=a1.w*w3.w;
            s[2][0]+=a2.x*w0.x; s[2][1]+=a2.x*w0.y; s[2][2]+=a2.x*w0.z; s[2][3]+=a2.x*w0.w;
            s[2][0]+=a2.y*w1.x; s[2][1]+=a2.y*w1.y; s[2][2]+=a2.y*w1.z; s[2][3]+=a2.y*w1.w;
            s[2][0]+=a2.z*w2.x; s[2][1]+=a2.z*w2.y; s[2][2]+=a2.z*w2.z; s[2][3]+=a2.z*w2.w;
            s[2][0]+=a2.w*w3.x; s[2][1]+=a2.w*w3.y; s[2][2]+=a2.w*w3.z; s[2][3]+=a2.w*w3.w;
            s[3][0]+=a3.x*w0.x; s[3][1]+=a3.x*w0.y; s[3][2]+=a3.x*w0.z; s[3][3]+=a3.x*w0.w;
            s[3][0]+=a3.y*w1.x; s[3][1]+=a3.y*w1.y; s[3][2]+=a3.y*w1.z; s[3][3]+=a3.y*w1.w;
            s[3][0]+=a3.z*w2.x; s[3][1]+=a3.z*w2.y; s[3][2]+=a3.z*w2.z; s[3][3]+=a3.z*w2.w;
            s[3][0]+=a3.w*w3.x; s[3][1]+=a3.w*w3.y; s[3][2]+=a3.w*w3.z; s[3][3]+=a3.w*w3.w;
        }
#pragma unroll
        for (int r = 0; r < 4; ++r) {
#pragma unroll
            for (int c = 0; c < 4; ++c) s[r][c] *= RSQRT_H;
            float tm = fmaxf(fmaxf(s[r][0], s[r][1]), fmaxf(s[r][2], s[r][3]));
            tm = fmaxf(tm, __shfl_xor(tm, 1));
            tm = fmaxf(tm, __shfl_xor(tm, 2));
            tm = fmaxf(tm, __shfl_xor(tm, 4));
            tm = fmaxf(tm, __shfl_xor(tm, 8));
            float mnew = fmaxf(mrow[r], tm);
            float ps = expf(s[r][0] - mnew) + expf(s[r][1] - mnew)
                     + expf(s[r][2] - mnew) + expf(s[r][3] - mnew);
            ps += __shfl_xor(ps, 1);
            ps += __shfl_xor(ps, 2);
            ps += __shfl_xor(ps, 4);
            ps += __shfl_xor(ps, 8);
            lrow[r] = lrow[r] * expf(mrow[r] - mnew) + ps;
            mrow[r] = mnew;
        }
    }

    float linv[4];
#pragma unroll
    for (int r = 0; r < 4; ++r) linv[r] = 1.f / lrow[r];

    // ---------------- pass B: column sums of attn
    for (int mt = 0; mt < 8; ++mt) {
        __syncthreads();
        int node0 = g * NPG + mt * 64;
#pragma unroll
        for (int i = 0; i < 8; ++i) {
            int idx = t + 256 * i;
            int d = idx >> 4, cq = idx & 15;
            *(float4*)&Kt[d][cq * 4] =
                *(const float4*)&kT[(size_t)d * NN + node0 + cq * 4];
        }
        __syncthreads();
        float s[4][4] = {{0.f}};
#pragma unroll 2
        for (int kk = 0; kk < 128; kk += 4) {
            float4 a0 = *(const float4*)&Ql[rg * 4 + 0][kk];
            float4 a1 = *(const float4*)&Ql[rg * 4 + 1][kk];
            float4 a2 = *(const float4*)&Ql[rg * 4 + 2][kk];
            float4 a3 = *(const float4*)&Ql[rg * 4 + 3][kk];
            float4 w0 = *(const float4*)&Kt[kk + 0][cg * 4];
            float4 w1 = *(const float4*)&Kt[kk + 1][cg * 4];
            float4 w2 = *(const float4*)&Kt[kk + 2][cg * 4];
            float4 w3 = *(const float4*)&Kt[kk + 3][cg * 4];
            s[0][0]+=a0.x*w0.x; s[0][1]+=a0.x*w0.y; s[0][2]+=a0.x*w0.z; s[0][3]+=a0.x*w0.w;
            s[0][0]+=a0.y*w1.x; s[0][1]+=a0.y*w1.y; s[0][2]+=a0.y*w1.z; s[0][3]+=a0.y*w1.w;
            s[0][0]+=a0.z*w2.x; s[0][1]+=a0.z*w2.y; s[0][2]+=a0.z*w2.z; s[0][3]+=a0.z*w2.w;
            s[0][0]+=a0.w*w3.x; s[0][1]+=a0.w*w3.y; s[0][2]+=a0.w*w3.z; s[0][3]+=a0.w*w3.w;
            s[1][0]+=a1.x*w0.x; s[1][1]+=a1.x*w0.y; s[1][2]+=a1.x*w0.z; s[1][3]+=a1.x*w0.w;
            s[1][0]+=a1.y*w1.x; s[1][1]+=a1.y*w1.y; s[1][2]+=a1.y*w1.z; s[1][3]+=a1.y*w1.w;
            s[1][0]+=a1.z*w2.x; s[1][1]+=a1.z*w2.y; s[1][2]+=a1.z*w2.z; s[1][3]+=a1.z*w2.w;
            s[1][0]+=a1.w*w3.x; s[1][1]+=a1.w*w3.y; s[1][2]+=a1.w*w3.z; s[1][3]+=a1.w*w3.w;
            s[2][0]+=a2.x*w0.x; s[2][1]+=a2.x*w0.y; s[2][2]+=a2.x*w0.z; s[2][3]+=a2.x*w0.w;
            s[2][0]+=a2.y*w1.x; s[2][1]+=a2.y*w1.y; s[2][2]+=a2.y*w1.z; s[2][3]+=a2.y*w1.w;
            s[2][0]+=a2.z*w2.x; s[2][1]+=a2.z*w2.y; s[2][2]+=a2.z*w2.z; s[2][3]+=a2.z*w2.w;
            s[2][0]+=a2.w*w3.x; s[2][1]+=a2.w*w3.y; s[2][2]+=a2.w*w3.z; s[2][3]+=a2.w*w3.w;
            s[3][0]+=a3.x*w0.x; s[3][1]+=a3.x*w0.y; s[3][2]+=a3.x*w0.z; s[3][3]+=a3.x*w0.w;
            s[3][0]+=a3.y*w1.x; s[3][1]+=a3.y*w1.y; s[3][2]+=a3.y*w1.z; s[3][3]+=a3.y*w1.w;
            s[3][0]+=a3.z*w2.x; s[3][1]+=a3.z*w2.y; s[3][2]+=a3.z*w2.z; s[3][3]+=a3.z*w2.w;
            s[3][0]+=a3.w*w3.x; s[3][1]+=a3.w*w3.y; s[3][2]+=a3.w*w3.z; s[3][3]+=a3.w*w3.w;
        }
        float pc[4];
#pragma unroll
        for (int c = 0; c < 4; ++c) {
            pc[c] = expf(s[0][c] * RSQRT_H - mrow[0]) * linv[0]
                  + expf(s[1][c] * RSQRT_H - mrow[1]) * linv[1]
                  + expf(s[2][c] * RSQRT_H - mrow[2]) * linv[2]
                  + expf(s[3][c] * RSQRT_H - mrow[3]) * linv[3];
            pc[c] += __shfl_xor(pc[c], 16);
            pc[c] += __shfl_xor(pc[c], 32);
        }
        if ((t & 63) < 16) {
#pragma unroll
            for (int c = 0; c < 4; ++c)
                atomicAdd(&wl[mt * 64 + cg * 4 + c], pc[c]);
        }
    }
    __syncthreads();
    atomicAdd(&wsum[g * NPG + t],       wl[t]       * (1.f / NPG));
    atomicAdd(&wsum[g * NPG + t + 256], wl[t + 256] * (1.f / NPG));
}

// ---------------------------------------------------------------- pool + head
__global__ __launch_bounds__(128) void k_head(
    const float* __restrict__ wsum,  // [64][512] (already includes 1/n)
    const float* __restrict__ h,     // [N][128]
    const float* __restrict__ Wv, const float* __restrict__ bv,
    const float* __restrict__ Wh1, const float* __restrict__ bh1,
    const float* __restrict__ Wh2, const float* __restrict__ bh2,
    float* __restrict__ out)
{
    __shared__ float ul[128];
    __shared__ float pl[128];
    __shared__ float r1l[64];
    int g = blockIdx.x, t = threadIdx.x;
    const float* hg = h + (size_t)g * NPG * HD;
    const float* wg = wsum + g * NPG;
    float u = 0.f;
    for (int m = 0; m < NPG; ++m) u += wg[m] * hg[m * HD + t];
    ul[t] = u;
    __syncthreads();
    float pv = bv[t];
    for (int d = 0; d < HD; ++d) pv += ul[d] * Wv[d * HD + t];
    pl[t] = pv;
    __syncthreads();
    if (t < 64) {
        float r1 = bh1[t];
        for (int d = 0; d < HD; ++d) r1 += pl[d] * Wh1[d * 64 + t];
        r1l[t] = fmaxf(r1, 0.f);
    }
    __syncthreads();
    if (t == 0) {
        float o = bh2[0];
        for (int j = 0; j < 64; ++j) o += r1l[j] * Wh2[j];
        out[g] = o;
    }
}

// ---------------------------------------------------------------- launch
extern "C" void kernel_launch(void* const* d_in, const int* in_sizes, int n_in,
                              void* d_out, int out_size, void* d_ws, size_t ws_size,
                              hipStream_t stream) {
    const float* x   = (const float*)d_in[0];
    const int* edge  = (const int*)d_in[1];
    // d_in[2] = batch (unused: batch = arange // 512 exactly)
    const float* W1  = (const float*)d_in[3];
    const float* b1  = (const float*)d_in[4];
    const float* W2  = (const float*)d_in[5];
    const float* b2  = (const float*)d_in[6];
    const float* Wq  = (const float*)d_in[7];
    const float* bq  = (const float*)d_in[8];
    const float* Wk  = (const float*)d_in[9];
    const float* bk  = (const float*)d_in[10];
    const float* Wv  = (const float*)d_in[11];
    const float* bv  = (const float*)d_in[12];
    const float* Wh1 = (const float*)d_in[13];
    const float* bh1 = (const float*)d_in[14];
    const float* Wh2 = (const float*)d_in[15];
    const float* bh2 = (const float*)d_in[16];
    float* out = (float*)d_out;

    int E = in_sizes[1] / 2;
    const int* src = edge;
    const int* dst = edge + E;

    // workspace layout (tbuf doubles as qbuf: tbuf is dead after conv2's agg)
    float* tbuf = (float*)d_ws;                      // [N][128]
    float* hbuf = tbuf + (size_t)NN * HD;            // [N][128]
    float* kTb  = hbuf + (size_t)NN * HD;            // [128][N]
    float* wcol = kTb + (size_t)NN * HD;             // [64][512]
    float* dinv = wcol + GG * NPG;                   // [N]
    int* deg    = (int*)(dinv + NN);                 // [N]
    int* rowoff = deg + NN;                          // [N+1]
    int* cursor = rowoff + (NN + 1);                 // [N]
    int* csr    = cursor + NN;                       // [E]
    float* qbuf = tbuf;

    int eb = (E + 255) / 256;

    k_init<<<NN / 256, 256, 0, stream>>>(deg, cursor, wcol);
    k_deg<<<eb, 256, 0, stream>>>(dst, deg, E);
    k_scan<<<1, 256, 0, stream>>>(deg, rowoff);
    k_dinv<<<NN / 256, 256, 0, stream>>>(deg, dinv);
    k_csr<<<eb, 256, 0, stream>>>(src, dst, rowoff, cursor, csr, E);

    dim3 ggrid(NN / 64, 2);
    // conv1
    k_gemm<0, 0><<<ggrid, 256, 0, stream>>>(x, W1, nullptr, tbuf, NN);
    k_agg<<<NN, 128, 0, stream>>>(tbuf, dinv, rowoff, csr, b1, hbuf);
    // conv2
    k_gemm<0, 0><<<ggrid, 256, 0, stream>>>(hbuf, W2, nullptr, tbuf, NN);
    k_agg<<<NN, 128, 0, stream>>>(tbuf, dinv, rowoff, csr, b2, hbuf);
    // q (normal; reuses tbuf), k (transposed out)
    k_gemm<0, 1><<<ggrid, 256, 0, stream>>>(hbuf, Wq, bq, qbuf, NN);
    k_gemm<1, 1><<<ggrid, 256, 0, stream>>>(hbuf, Wk, bk, kTb, NN);
    // attention column sums
    k_attn<<<GG * 8, 256, 0, stream>>>(qbuf, kTb, wcol);
    // pool + MLP head
    k_head<<<GG, 128, 0, stream>>>(wcol, hbuf, Wv, bv, Wh1, bh1, Wh2, bh2, out);
}

// Round 3
// 394.010 us; speedup vs baseline: 1.5978x; 1.5978x over previous
//
#include <hip/hip_runtime.h>
#include <hip/hip_bf16.h>

// Problem constants (fixed by the reference)
#define NN 32768      // nodes
#define GG 64         // graphs
#define NPG 512       // nodes per graph
#define HD 128        // feature/hidden width
#define MAXD 64       // ELL pad (mean degree 16, P(>64) ~ 1e-26)
#define RSQRT_H 0.08838834764831845f  // 1/sqrt(128)

// ---------------------------------------------------------------- init / ELL
__global__ void k_init(int* __restrict__ cursor, float* __restrict__ wcol,
                       float* __restrict__ ubuf) {
    int i = blockIdx.x * 256 + threadIdx.x;   // 32768 threads
    cursor[i] = 0; wcol[i] = 0.f;
    if (i < GG * HD) ubuf[i] = 0.f;
}

__global__ void k_fill(const int* __restrict__ src, const int* __restrict__ dst,
                       int* __restrict__ cursor, int* __restrict__ ell, int E) {
    int e = blockIdx.x * 256 + threadIdx.x;
    if (e < E) {
        int d = dst[e];
        int slot = atomicAdd(&cursor[d], 1);
        if (slot < MAXD) ell[d * MAXD + slot] = src[e];
    }
}

__global__ void k_dinv(const int* __restrict__ cursor, float* __restrict__ dinv) {
    int i = blockIdx.x * 256 + threadIdx.x;
    int cnt = min(cursor[i], MAXD);
    dinv[i] = rsqrtf((float)(cnt + 1));        // +1 self-loop
}

// ---------------------------------------------------------------- GEMM [M,128]@[128,128]
// 64x64 tile, 256 threads, 4x4 micro-tile. A row-major in LDS (pad 132),
// W k-major (pad 68). All hot-loop LDS reads are <=2-way conflicts (free).
#define FMA_ROW(r, av, wv) \
    acc[r][0] += (av)*(wv).x; acc[r][1] += (av)*(wv).y; \
    acc[r][2] += (av)*(wv).z; acc[r][3] += (av)*(wv).w;

__global__ __launch_bounds__(256) void k_gemm(
    const float* __restrict__ A, const float* __restrict__ W,
    float* __restrict__ out, int M)
{
    __shared__ float Al[64][132];
    __shared__ float Wt[128][68];
    int t = threadIdx.x;
    int row0 = blockIdx.x * 64;
    int col0 = blockIdx.y * 64;

    const float4* A4 = (const float4*)(A + (size_t)row0 * HD);
#pragma unroll
    for (int i = 0; i < 8; ++i) {
        int idx = t + 256 * i;          // 2048 float4 = 64 rows x 32 kquads
        *(float4*)&Al[idx >> 5][(idx & 31) * 4] = A4[idx];
    }
    const float4* W4 = (const float4*)W;
#pragma unroll
    for (int i = 0; i < 8; ++i) {
        int idx = t + 256 * i;          // 2048 float4 = 128 k x 16 colquads
        int k = idx >> 4, cq = idx & 15;
        *(float4*)&Wt[k][cq * 4] = W4[k * 32 + (col0 >> 2) + cq];
    }
    __syncthreads();

    int cg = t & 15, rg = t >> 4;
    float acc[4][4] = {{0.f}};
#pragma unroll 2
    for (int kk = 0; kk < 128; kk += 4) {
        float4 a0 = *(const float4*)&Al[rg * 4 + 0][kk];
        float4 a1 = *(const float4*)&Al[rg * 4 + 1][kk];
        float4 a2 = *(const float4*)&Al[rg * 4 + 2][kk];
        float4 a3 = *(const float4*)&Al[rg * 4 + 3][kk];
        float4 w0 = *(const float4*)&Wt[kk + 0][cg * 4];
        float4 w1 = *(const float4*)&Wt[kk + 1][cg * 4];
        float4 w2 = *(const float4*)&Wt[kk + 2][cg * 4];
        float4 w3 = *(const float4*)&Wt[kk + 3][cg * 4];
        FMA_ROW(0, a0.x, w0) FMA_ROW(0, a0.y, w1) FMA_ROW(0, a0.z, w2) FMA_ROW(0, a0.w, w3)
        FMA_ROW(1, a1.x, w0) FMA_ROW(1, a1.y, w1) FMA_ROW(1, a1.z, w2) FMA_ROW(1, a1.w, w3)
        FMA_ROW(2, a2.x, w0) FMA_ROW(2, a2.y, w1) FMA_ROW(2, a2.z, w2) FMA_ROW(2, a2.w, w3)
        FMA_ROW(3, a3.x, w0) FMA_ROW(3, a3.y, w1) FMA_ROW(3, a3.z, w2) FMA_ROW(3, a3.w, w3)
    }
#pragma unroll
    for (int r = 0; r < 4; ++r) {
        int row = row0 + rg * 4 + r;
        *(float4*)&out[(size_t)row * HD + col0 + cg * 4] =
            make_float4(acc[r][0], acc[r][1], acc[r][2], acc[r][3]);
    }
}

// Fused Q/K projection: stage A-tile once, two K-loops. q written normal,
// k written transposed [HD][NN] via LDS restage (coalesced).
__global__ __launch_bounds__(256) void k_gemm_qk(
    const float* __restrict__ A,
    const float* __restrict__ Wq, const float* __restrict__ bq,
    const float* __restrict__ Wk, const float* __restrict__ bk,
    float* __restrict__ qout, float* __restrict__ kTout, int M)
{
    __shared__ float Al[64][132];
    __shared__ float Wt[128][68];
    int t = threadIdx.x;
    int row0 = blockIdx.x * 64;
    int col0 = blockIdx.y * 64;
    int cg = t & 15, rg = t >> 4;

    const float4* A4 = (const float4*)(A + (size_t)row0 * HD);
#pragma unroll
    for (int i = 0; i < 8; ++i) {
        int idx = t + 256 * i;
        *(float4*)&Al[idx >> 5][(idx & 31) * 4] = A4[idx];
    }
    const float4* Wq4 = (const float4*)Wq;
#pragma unroll
    for (int i = 0; i < 8; ++i) {
        int idx = t + 256 * i;
        int k = idx >> 4, cq = idx & 15;
        *(float4*)&Wt[k][cq * 4] = Wq4[k * 32 + (col0 >> 2) + cq];
    }
    __syncthreads();

    {
        float acc[4][4] = {{0.f}};
#pragma unroll 2
        for (int kk = 0; kk < 128; kk += 4) {
            float4 a0 = *(const float4*)&Al[rg * 4 + 0][kk];
            float4 a1 = *(const float4*)&Al[rg * 4 + 1][kk];
            float4 a2 = *(const float4*)&Al[rg * 4 + 2][kk];
            float4 a3 = *(const float4*)&Al[rg * 4 + 3][kk];
            float4 w0 = *(const float4*)&Wt[kk + 0][cg * 4];
            float4 w1 = *(const float4*)&Wt[kk + 1][cg * 4];
            float4 w2 = *(const float4*)&Wt[kk + 2][cg * 4];
            float4 w3 = *(const float4*)&Wt[kk + 3][cg * 4];
            FMA_ROW(0, a0.x, w0) FMA_ROW(0, a0.y, w1) FMA_ROW(0, a0.z, w2) FMA_ROW(0, a0.w, w3)
            FMA_ROW(1, a1.x, w0) FMA_ROW(1, a1.y, w1) FMA_ROW(1, a1.z, w2) FMA_ROW(1, a1.w, w3)
            FMA_ROW(2, a2.x, w0) FMA_ROW(2, a2.y, w1) FMA_ROW(2, a2.z, w2) FMA_ROW(2, a2.w, w3)
            FMA_ROW(3, a3.x, w0) FMA_ROW(3, a3.y, w1) FMA_ROW(3, a3.z, w2) FMA_ROW(3, a3.w, w3)
        }
        int c = col0 + cg * 4;
        float4 bqv = make_float4(bq[c], bq[c+1], bq[c+2], bq[c+3]);
#pragma unroll
        for (int r = 0; r < 4; ++r) {
            int row = row0 + rg * 4 + r;
            *(float4*)&qout[(size_t)row * HD + c] =
                make_float4(acc[r][0] + bqv.x, acc[r][1] + bqv.y,
                            acc[r][2] + bqv.z, acc[r][3] + bqv.w);
        }
    }
    __syncthreads();                     // everyone done reading Wt
    const float4* Wk4 = (const float4*)Wk;
#pragma unroll
    for (int i = 0; i < 8; ++i) {
        int idx = t + 256 * i;
        int k = idx >> 4, cq = idx & 15;
        *(float4*)&Wt[k][cq * 4] = Wk4[k * 32 + (col0 >> 2) + cq];
    }
    __syncthreads();

    float acc[4][4] = {{0.f}};
#pragma unroll 2
    for (int kk = 0; kk < 128; kk += 4) {
        float4 a0 = *(const float4*)&Al[rg * 4 + 0][kk];
        float4 a1 = *(const float4*)&Al[rg * 4 + 1][kk];
        float4 a2 = *(const float4*)&Al[rg * 4 + 2][kk];
        float4 a3 = *(const float4*)&Al[rg * 4 + 3][kk];
        float4 w0 = *(const float4*)&Wt[kk + 0][cg * 4];
        float4 w1 = *(const float4*)&Wt[kk + 1][cg * 4];
        float4 w2 = *(const float4*)&Wt[kk + 2][cg * 4];
        float4 w3 = *(const float4*)&Wt[kk + 3][cg * 4];
        FMA_ROW(0, a0.x, w0) FMA_ROW(0, a0.y, w1) FMA_ROW(0, a0.z, w2) FMA_ROW(0, a0.w, w3)
        FMA_ROW(1, a1.x, w0) FMA_ROW(1, a1.y, w1) FMA_ROW(1, a1.z, w2) FMA_ROW(1, a1.w, w3)
        FMA_ROW(2, a2.x, w0) FMA_ROW(2, a2.y, w1) FMA_ROW(2, a2.z, w2) FMA_ROW(2, a2.w, w3)
        FMA_ROW(3, a3.x, w0) FMA_ROW(3, a3.y, w1) FMA_ROW(3, a3.z, w2) FMA_ROW(3, a3.w, w3)
    }
    // transpose epilogue through LDS (Al is dead)
    __syncthreads();
    float* Sl = &Al[0][0];               // 64x64 tile, stride 68
#pragma unroll
    for (int r = 0; r < 4; ++r)
        *(float4*)&Sl[(rg * 4 + r) * 68 + cg * 4] =
            make_float4(acc[r][0], acc[r][1], acc[r][2], acc[r][3]);
    __syncthreads();
#pragma unroll
    for (int i = 0; i < 4; ++i) {
        int idx = t + 256 * i;           // 1024 float4 = 64 cols x 16 rowquads
        int c = idx >> 4, rq = idx & 15;
        float b = bk[col0 + c];
        float4 o = make_float4(Sl[(rq * 4 + 0) * 68 + c] + b,
                               Sl[(rq * 4 + 1) * 68 + c] + b,
                               Sl[(rq * 4 + 2) * 68 + c] + b,
                               Sl[(rq * 4 + 3) * 68 + c] + b);
        *(float4*)&kTout[(size_t)(col0 + c) * M + row0 + rq * 4] = o;
    }
}

// ---------------------------------------------------------------- aggregation
// one block (128 threads) per node: acc = self + sum over in-edges, then +b, relu
__global__ __launch_bounds__(128) void k_agg(
    const float* __restrict__ tmat, const float* __restrict__ dinv,
    const int* __restrict__ cursor, const int* __restrict__ ell,
    const float* __restrict__ bias, float* __restrict__ hout)
{
    int i = blockIdx.x, t = threadIdx.x;
    float di = dinv[i];
    float acc = tmat[(size_t)i * HD + t] * di * di;     // self-loop
    int cnt = min(cursor[i], MAXD);
    const int* row = ell + (size_t)i * MAXD;
    for (int e = 0; e < cnt; ++e) {
        int s = row[e];
        acc += tmat[(size_t)s * HD + t] * (dinv[s] * di);
    }
    hout[(size_t)i * HD + t] = fmaxf(acc + bias[t], 0.f);
}

// ---------------------------------------------------------------- attention
// Single pass: per (graph, 64-row q-tile), S kept in 128 VGPRs (occupancy is
// grid-bound at 2 blocks/CU so the registers are free). Post-hoc max/sumexp,
// then attn column sums -> global w (softmax weights for pooled = sum w*h).
#define PFMA(mt, r, av, wv) \
    p[mt][r][0] += (av)*(wv).x; p[mt][r][1] += (av)*(wv).y; \
    p[mt][r][2] += (av)*(wv).z; p[mt][r][3] += (av)*(wv).w;

__global__ __launch_bounds__(256, 2) void k_attn(
    const float* __restrict__ q,    // [N][128]
    const float* __restrict__ kT,   // [128][N]
    float* __restrict__ wsum)       // [64][512]
{
    __shared__ float Ql[64][132];
    __shared__ float Kt[128][68];
    __shared__ float wl[512];
    int t = threadIdx.x;
    int g = blockIdx.x >> 3;
    int qt = blockIdx.x & 7;
    int qrow0 = g * NPG + qt * 64;

    wl[t] = 0.f; wl[t + 256] = 0.f;
    const float4* q4 = (const float4*)(q + (size_t)qrow0 * HD);
#pragma unroll
    for (int i = 0; i < 8; ++i) {
        int idx = t + 256 * i;
        *(float4*)&Ql[idx >> 5][(idx & 31) * 4] = q4[idx];
    }
    int cg = t & 15, rg = t >> 4;
    float p[8][4][4];    // raw scores, statically indexed (mt loop unrolled)

#pragma unroll
    for (int mt = 0; mt < 8; ++mt) {
        __syncthreads();
        int node0 = g * NPG + mt * 64;
#pragma unroll
        for (int i = 0; i < 8; ++i) {
            int idx = t + 256 * i;      // 2048 float4 = 128 d x 16 colquads
            int d = idx >> 4, cq = idx & 15;
            *(float4*)&Kt[d][cq * 4] =
                *(const float4*)&kT[(size_t)d * NN + node0 + cq * 4];
        }
        __syncthreads();
#pragma unroll
        for (int r = 0; r < 4; ++r)
#pragma unroll
            for (int c = 0; c < 4; ++c) p[mt][r][c] = 0.f;
#pragma unroll 2
        for (int kk = 0; kk < 128; kk += 4) {
            float4 a0 = *(const float4*)&Ql[rg * 4 + 0][kk];
            float4 a1 = *(const float4*)&Ql[rg * 4 + 1][kk];
            float4 a2 = *(const float4*)&Ql[rg * 4 + 2][kk];
            float4 a3 = *(const float4*)&Ql[rg * 4 + 3][kk];
            float4 w0 = *(const float4*)&Kt[kk + 0][cg * 4];
            float4 w1 = *(const float4*)&Kt[kk + 1][cg * 4];
            float4 w2 = *(const float4*)&Kt[kk + 2][cg * 4];
            float4 w3 = *(const float4*)&Kt[kk + 3][cg * 4];
            PFMA(mt, 0, a0.x, w0) PFMA(mt, 0, a0.y, w1) PFMA(mt, 0, a0.z, w2) PFMA(mt, 0, a0.w, w3)
            PFMA(mt, 1, a1.x, w0) PFMA(mt, 1, a1.y, w1) PFMA(mt, 1, a1.z, w2) PFMA(mt, 1, a1.w, w3)
            PFMA(mt, 2, a2.x, w0) PFMA(mt, 2, a2.y, w1) PFMA(mt, 2, a2.z, w2) PFMA(mt, 2, a2.w, w3)
            PFMA(mt, 3, a3.x, w0) PFMA(mt, 3, a3.y, w1) PFMA(mt, 3, a3.z, w2) PFMA(mt, 3, a3.w, w3)
        }
    }

    // row max (post-hoc, over stored raw scores)
    float mrow[4], linv[4];
#pragma unroll
    for (int r = 0; r < 4; ++r) {
        float m = p[0][r][0];
#pragma unroll
        for (int mt = 0; mt < 8; ++mt)
#pragma unroll
            for (int c = 0; c < 4; ++c) m = fmaxf(m, p[mt][r][c]);
        m = fmaxf(m, __shfl_xor(m, 1));
        m = fmaxf(m, __shfl_xor(m, 2));
        m = fmaxf(m, __shfl_xor(m, 4));
        m = fmaxf(m, __shfl_xor(m, 8));
        mrow[r] = m;
    }
    // exponentiate in place
#pragma unroll
    for (int mt = 0; mt < 8; ++mt)
#pragma unroll
        for (int r = 0; r < 4; ++r)
#pragma unroll
            for (int c = 0; c < 4; ++c)
                p[mt][r][c] = __expf((p[mt][r][c] - mrow[r]) * RSQRT_H);
    // row sumexp -> 1/l
#pragma unroll
    for (int r = 0; r < 4; ++r) {
        float l = 0.f;
#pragma unroll
        for (int mt = 0; mt < 8; ++mt)
#pragma unroll
            for (int c = 0; c < 4; ++c) l += p[mt][r][c];
        l += __shfl_xor(l, 1);
        l += __shfl_xor(l, 2);
        l += __shfl_xor(l, 4);
        l += __shfl_xor(l, 8);
        linv[r] = 1.f / l;
    }
    // column sums of normalized attention
#pragma unroll
    for (int mt = 0; mt < 8; ++mt) {
#pragma unroll
        for (int c = 0; c < 4; ++c) {
            float pc = p[mt][0][c] * linv[0] + p[mt][1][c] * linv[1]
                     + p[mt][2][c] * linv[2] + p[mt][3][c] * linv[3];
            pc += __shfl_xor(pc, 16);
            pc += __shfl_xor(pc, 32);
            if ((t & 63) < 16) atomicAdd(&wl[mt * 64 + cg * 4 + c], pc);
        }
    }
    __syncthreads();
    atomicAdd(&wsum[g * NPG + t],       wl[t]       * (1.f / NPG));
    atomicAdd(&wsum[g * NPG + t + 256], wl[t + 256] * (1.f / NPG));
}

// ---------------------------------------------------------------- pool + head
// u[g] = sum_m w[m] * h[m]  (512 blocks: 8 chunks of 64 rows per graph)
__global__ __launch_bounds__(128) void k_pool(
    const float* __restrict__ wsum, const float* __restrict__ h,
    float* __restrict__ ubuf)
{
    int b = blockIdx.x;
    int g = b >> 3, ch = b & 7;
    int t = threadIdx.x;
    const float* hg = h + ((size_t)g * NPG + ch * 64) * HD;
    const float* wg = wsum + g * NPG + ch * 64;
    float u = 0.f;
#pragma unroll 4
    for (int m = 0; m < 64; ++m) u += wg[m] * hg[m * HD + t];
    atomicAdd(&ubuf[g * HD + t], u);
}

__global__ __launch_bounds__(128) void k_head2(
    const float* __restrict__ ubuf,
    const float* __restrict__ Wv, const float* __restrict__ bv,
    const float* __restrict__ Wh1, const float* __restrict__ bh1,
    const float* __restrict__ Wh2, const float* __restrict__ bh2,
    float* __restrict__ out)
{
    __shared__ float pl[128];
    __shared__ float r1l[64];
    int g = blockIdx.x, t = threadIdx.x;
    const float* ug = ubuf + g * HD;
    float pv = bv[t];
    for (int d = 0; d < HD; ++d) pv += ug[d] * Wv[d * HD + t];
    pl[t] = pv;
    __syncthreads();
    if (t < 64) {
        float r1 = bh1[t];
        for (int d = 0; d < HD; ++d) r1 += pl[d] * Wh1[d * 64 + t];
        r1l[t] = fmaxf(r1, 0.f);
    }
    __syncthreads();
    if (t == 0) {
        float o = bh2[0];
        for (int j = 0; j < 64; ++j) o += r1l[j] * Wh2[j];
        out[g] = o;
    }
}

// ---------------------------------------------------------------- launch
extern "C" void kernel_launch(void* const* d_in, const int* in_sizes, int n_in,
                              void* d_out, int out_size, void* d_ws, size_t ws_size,
                              hipStream_t stream) {
    const float* x   = (const float*)d_in[0];
    const int* edge  = (const int*)d_in[1];
    // d_in[2] = batch (unused: batch = arange // 512 exactly)
    const float* W1  = (const float*)d_in[3];
    const float* b1  = (const float*)d_in[4];
    const float* W2  = (const float*)d_in[5];
    const float* b2  = (const float*)d_in[6];
    const float* Wq  = (const float*)d_in[7];
    const float* bq  = (const float*)d_in[8];
    const float* Wk  = (const float*)d_in[9];
    const float* bk  = (const float*)d_in[10];
    const float* Wv  = (const float*)d_in[11];
    const float* bv  = (const float*)d_in[12];
    const float* Wh1 = (const float*)d_in[13];
    const float* bh1 = (const float*)d_in[14];
    const float* Wh2 = (const float*)d_in[15];
    const float* bh2 = (const float*)d_in[16];
    float* out = (float*)d_out;

    int E = in_sizes[1] / 2;
    const int* src = edge;
    const int* dst = edge + E;

    // workspace layout (48.6 MB):
    //  tbuf/qbuf [N*HD] | hbuf [N*HD] | kTb [HD*N] (aliased by ELL int[N*64])
    //  | wcol | ubuf | dinv | cursor
    float* tbuf = (float*)d_ws;                      // [N][128] (also qbuf)
    float* hbuf = tbuf + (size_t)NN * HD;            // [N][128]
    float* kTb  = hbuf + (size_t)NN * HD;            // [128][N]
    float* wcol = kTb + (size_t)NN * HD;             // [64][512]
    float* ubuf = wcol + GG * NPG;                   // [64][128]
    float* dinv = ubuf + GG * HD;                    // [N]
    int* cursor = (int*)(dinv + NN);                 // [N] (doubles as deg)
    int* ell    = (int*)kTb;                         // [N][64], dead before kTb born
    float* qbuf = tbuf;

    int eb = (E + 255) / 256;
    dim3 ggrid(NN / 64, 2);

    // graph structure (ELL, no scan)
    k_init<<<NN / 256, 256, 0, stream>>>(cursor, wcol, ubuf);
    k_fill<<<eb, 256, 0, stream>>>(src, dst, cursor, ell, E);
    k_dinv<<<NN / 256, 256, 0, stream>>>(cursor, dinv);

    // conv1
    k_gemm<<<ggrid, 256, 0, stream>>>(x, W1, tbuf, NN);
    k_agg<<<NN, 128, 0, stream>>>(tbuf, dinv, cursor, ell, b1, hbuf);
    // conv2
    k_gemm<<<ggrid, 256, 0, stream>>>(hbuf, W2, tbuf, NN);
    k_agg<<<NN, 128, 0, stream>>>(tbuf, dinv, cursor, ell, b2, hbuf);
    // q + kT in one pass (ell dead from here; kTb reuses its space)
    k_gemm_qk<<<ggrid, 256, 0, stream>>>(hbuf, Wq, bq, Wk, bk, qbuf, kTb, NN);
    // attention column weights
    k_attn<<<GG * 8, 256, 0, stream>>>(qbuf, kTb, wcol);
    // pool + MLP head
    k_pool<<<GG * 8, 128, 0, stream>>>(wcol, hbuf, ubuf);
    k_head2<<<GG, 128, 0, stream>>>(ubuf, Wv, bv, Wh1, bh1, Wh2, bh2, out);
}

// Round 4
// 390.433 us; speedup vs baseline: 1.6125x; 1.0092x over previous
//
#include <hip/hip_runtime.h>
#include <hip/hip_bf16.h>

// Problem constants (fixed by the reference)
#define NN 32768      // nodes
#define GG 64         // graphs
#define NPG 512       // nodes per graph
#define HD 128        // feature/hidden width
#define MAXD 64       // ELL pad (mean degree 16, P(>64) ~ 1e-26)
#define RSQRT_H 0.08838834764831845f  // 1/sqrt(128)

// ---------------------------------------------------------------- ELL build
__global__ void k_fill(const int* __restrict__ src, const int* __restrict__ dst,
                       int* __restrict__ cursor, int* __restrict__ ell, int E) {
    int e = blockIdx.x * 256 + threadIdx.x;
    if (e < E) {
        int d = dst[e];
        int slot = atomicAdd(&cursor[d], 1);
        if (slot < MAXD) ell[d * MAXD + slot] = src[e];
    }
}

// ---------------------------------------------------------------- GEMM [M,128]@[128,128]
// 64x64 tile, 256 threads, 4x4 micro-tile. A row-major in LDS (pad 132),
// W k-major (pad 68). All hot-loop LDS reads are broadcast or 2-way (free).
#define FMA_ROW(r, av, wv) \
    acc[r][0] += (av)*(wv).x; acc[r][1] += (av)*(wv).y; \
    acc[r][2] += (av)*(wv).z; acc[r][3] += (av)*(wv).w;

__global__ __launch_bounds__(256) void k_gemm(
    const float* __restrict__ A, const float* __restrict__ W,
    float* __restrict__ out, int M)
{
    __shared__ float Al[64][132];
    __shared__ float Wt[128][68];
    int t = threadIdx.x;
    int row0 = blockIdx.x * 64;
    int col0 = blockIdx.y * 64;

    const float4* A4 = (const float4*)(A + (size_t)row0 * HD);
#pragma unroll
    for (int i = 0; i < 8; ++i) {
        int idx = t + 256 * i;          // 2048 float4 = 64 rows x 32 kquads
        *(float4*)&Al[idx >> 5][(idx & 31) * 4] = A4[idx];
    }
    const float4* W4 = (const float4*)W;
#pragma unroll
    for (int i = 0; i < 8; ++i) {
        int idx = t + 256 * i;          // 2048 float4 = 128 k x 16 colquads
        int k = idx >> 4, cq = idx & 15;
        *(float4*)&Wt[k][cq * 4] = W4[k * 32 + (col0 >> 2) + cq];
    }
    __syncthreads();

    int cg = t & 15, rg = t >> 4;
    float acc[4][4] = {{0.f}};
#pragma unroll 2
    for (int kk = 0; kk < 128; kk += 4) {
        float4 a0 = *(const float4*)&Al[rg * 4 + 0][kk];
        float4 a1 = *(const float4*)&Al[rg * 4 + 1][kk];
        float4 a2 = *(const float4*)&Al[rg * 4 + 2][kk];
        float4 a3 = *(const float4*)&Al[rg * 4 + 3][kk];
        float4 w0 = *(const float4*)&Wt[kk + 0][cg * 4];
        float4 w1 = *(const float4*)&Wt[kk + 1][cg * 4];
        float4 w2 = *(const float4*)&Wt[kk + 2][cg * 4];
        float4 w3 = *(const float4*)&Wt[kk + 3][cg * 4];
        FMA_ROW(0, a0.x, w0) FMA_ROW(0, a0.y, w1) FMA_ROW(0, a0.z, w2) FMA_ROW(0, a0.w, w3)
        FMA_ROW(1, a1.x, w0) FMA_ROW(1, a1.y, w1) FMA_ROW(1, a1.z, w2) FMA_ROW(1, a1.w, w3)
        FMA_ROW(2, a2.x, w0) FMA_ROW(2, a2.y, w1) FMA_ROW(2, a2.z, w2) FMA_ROW(2, a2.w, w3)
        FMA_ROW(3, a3.x, w0) FMA_ROW(3, a3.y, w1) FMA_ROW(3, a3.z, w2) FMA_ROW(3, a3.w, w3)
    }
#pragma unroll
    for (int r = 0; r < 4; ++r) {
        int row = row0 + rg * 4 + r;
        *(float4*)&out[(size_t)row * HD + col0 + cg * 4] =
            make_float4(acc[r][0], acc[r][1], acc[r][2], acc[r][3]);
    }
}

// Fused Q/K projection: stage A-tile once, two K-loops. q written normal,
// k written transposed [HD][NN] via LDS restage (coalesced).
__global__ __launch_bounds__(256) void k_gemm_qk(
    const float* __restrict__ A,
    const float* __restrict__ Wq, const float* __restrict__ bq,
    const float* __restrict__ Wk, const float* __restrict__ bk,
    float* __restrict__ qout, float* __restrict__ kTout, int M)
{
    __shared__ float Al[64][132];
    __shared__ float Wt[128][68];
    int t = threadIdx.x;
    int row0 = blockIdx.x * 64;
    int col0 = blockIdx.y * 64;
    int cg = t & 15, rg = t >> 4;

    const float4* A4 = (const float4*)(A + (size_t)row0 * HD);
#pragma unroll
    for (int i = 0; i < 8; ++i) {
        int idx = t + 256 * i;
        *(float4*)&Al[idx >> 5][(idx & 31) * 4] = A4[idx];
    }
    const float4* Wq4 = (const float4*)Wq;
#pragma unroll
    for (int i = 0; i < 8; ++i) {
        int idx = t + 256 * i;
        int k = idx >> 4, cq = idx & 15;
        *(float4*)&Wt[k][cq * 4] = Wq4[k * 32 + (col0 >> 2) + cq];
    }
    __syncthreads();

    {
        float acc[4][4] = {{0.f}};
#pragma unroll 2
        for (int kk = 0; kk < 128; kk += 4) {
            float4 a0 = *(const float4*)&Al[rg * 4 + 0][kk];
            float4 a1 = *(const float4*)&Al[rg * 4 + 1][kk];
            float4 a2 = *(const float4*)&Al[rg * 4 + 2][kk];
            float4 a3 = *(const float4*)&Al[rg * 4 + 3][kk];
            float4 w0 = *(const float4*)&Wt[kk + 0][cg * 4];
            float4 w1 = *(const float4*)&Wt[kk + 1][cg * 4];
            float4 w2 = *(const float4*)&Wt[kk + 2][cg * 4];
            float4 w3 = *(const float4*)&Wt[kk + 3][cg * 4];
            FMA_ROW(0, a0.x, w0) FMA_ROW(0, a0.y, w1) FMA_ROW(0, a0.z, w2) FMA_ROW(0, a0.w, w3)
            FMA_ROW(1, a1.x, w0) FMA_ROW(1, a1.y, w1) FMA_ROW(1, a1.z, w2) FMA_ROW(1, a1.w, w3)
            FMA_ROW(2, a2.x, w0) FMA_ROW(2, a2.y, w1) FMA_ROW(2, a2.z, w2) FMA_ROW(2, a2.w, w3)
            FMA_ROW(3, a3.x, w0) FMA_ROW(3, a3.y, w1) FMA_ROW(3, a3.z, w2) FMA_ROW(3, a3.w, w3)
        }
        int c = col0 + cg * 4;
        float4 bqv = make_float4(bq[c], bq[c+1], bq[c+2], bq[c+3]);
#pragma unroll
        for (int r = 0; r < 4; ++r) {
            int row = row0 + rg * 4 + r;
            *(float4*)&qout[(size_t)row * HD + c] =
                make_float4(acc[r][0] + bqv.x, acc[r][1] + bqv.y,
                            acc[r][2] + bqv.z, acc[r][3] + bqv.w);
        }
    }
    __syncthreads();                     // everyone done reading Wt
    const float4* Wk4 = (const float4*)Wk;
#pragma unroll
    for (int i = 0; i < 8; ++i) {
        int idx = t + 256 * i;
        int k = idx >> 4, cq = idx & 15;
        *(float4*)&Wt[k][cq * 4] = Wk4[k * 32 + (col0 >> 2) + cq];
    }
    __syncthreads();

    float acc[4][4] = {{0.f}};
#pragma unroll 2
    for (int kk = 0; kk < 128; kk += 4) {
        float4 a0 = *(const float4*)&Al[rg * 4 + 0][kk];
        float4 a1 = *(const float4*)&Al[rg * 4 + 1][kk];
        float4 a2 = *(const float4*)&Al[rg * 4 + 2][kk];
        float4 a3 = *(const float4*)&Al[rg * 4 + 3][kk];
        float4 w0 = *(const float4*)&Wt[kk + 0][cg * 4];
        float4 w1 = *(const float4*)&Wt[kk + 1][cg * 4];
        float4 w2 = *(const float4*)&Wt[kk + 2][cg * 4];
        float4 w3 = *(const float4*)&Wt[kk + 3][cg * 4];
        FMA_ROW(0, a0.x, w0) FMA_ROW(0, a0.y, w1) FMA_ROW(0, a0.z, w2) FMA_ROW(0, a0.w, w3)
        FMA_ROW(1, a1.x, w0) FMA_ROW(1, a1.y, w1) FMA_ROW(1, a1.z, w2) FMA_ROW(1, a1.w, w3)
        FMA_ROW(2, a2.x, w0) FMA_ROW(2, a2.y, w1) FMA_ROW(2, a2.z, w2) FMA_ROW(2, a2.w, w3)
        FMA_ROW(3, a3.x, w0) FMA_ROW(3, a3.y, w1) FMA_ROW(3, a3.z, w2) FMA_ROW(3, a3.w, w3)
    }
    // transpose epilogue through LDS (Al is dead)
    __syncthreads();
    float* Sl = &Al[0][0];               // 64x64 tile, stride 68
#pragma unroll
    for (int r = 0; r < 4; ++r)
        *(float4*)&Sl[(rg * 4 + r) * 68 + cg * 4] =
            make_float4(acc[r][0], acc[r][1], acc[r][2], acc[r][3]);
    __syncthreads();
#pragma unroll
    for (int i = 0; i < 4; ++i) {
        int idx = t + 256 * i;           // 1024 float4 = 64 cols x 16 rowquads
        int c = idx >> 4, rq = idx & 15;
        float b = bk[col0 + c];
        float4 o = make_float4(Sl[(rq * 4 + 0) * 68 + c] + b,
                               Sl[(rq * 4 + 1) * 68 + c] + b,
                               Sl[(rq * 4 + 2) * 68 + c] + b,
                               Sl[(rq * 4 + 3) * 68 + c] + b);
        *(float4*)&kTout[(size_t)(col0 + c) * M + row0 + rq * 4] = o;
    }
}

// ---------------------------------------------------------------- aggregation
// one block (128 threads) per node; dinv computed on the fly from cursor
__global__ __launch_bounds__(128) void k_agg(
    const float* __restrict__ tmat, const int* __restrict__ cursor,
    const int* __restrict__ ell, const float* __restrict__ bias,
    float* __restrict__ hout)
{
    int i = blockIdx.x, t = threadIdx.x;
    int cnt = min(cursor[i], MAXD);
    float di = rsqrtf((float)(cnt + 1));
    float acc = tmat[(size_t)i * HD + t] * di * di;     // self-loop
    const int* row = ell + (size_t)i * MAXD;
    int e = 0;
    for (; e + 2 <= cnt; e += 2) {                      // 2-edge ILP unroll
        int s0 = row[e], s1 = row[e + 1];
        float w0 = rsqrtf((float)(min(cursor[s0], MAXD) + 1)) * di;
        float w1 = rsqrtf((float)(min(cursor[s1], MAXD) + 1)) * di;
        acc += tmat[(size_t)s0 * HD + t] * w0 + tmat[(size_t)s1 * HD + t] * w1;
    }
    if (e < cnt) {
        int s0 = row[e];
        acc += tmat[(size_t)s0 * HD + t]
             * rsqrtf((float)(min(cursor[s0], MAXD) + 1)) * di;
    }
    hout[(size_t)i * HD + t] = fmaxf(acc + bias[t], 0.f);
}

// ---------------------------------------------------------------- attention
// Single pass, S in registers; T14 async-stage: next K-tile's global loads
// issued into regs before computing current tile (latency hides under FMA).
// Output: per-(g,qt) weight slices wpart[g][qt][512] (no atomics, no init).
#define PFMA(mt, r, av, wv) \
    p[mt][r][0] += (av)*(wv).x; p[mt][r][1] += (av)*(wv).y; \
    p[mt][r][2] += (av)*(wv).z; p[mt][r][3] += (av)*(wv).w;

__global__ __launch_bounds__(256, 2) void k_attn(
    const float* __restrict__ q,    // [N][128]
    const float* __restrict__ kT,   // [128][N]
    float* __restrict__ wpart)      // [64][8][512]
{
    __shared__ float Ql[64][132];
    __shared__ float Kt[128][68];
    __shared__ float wl[512];
    int t = threadIdx.x;
    int g = blockIdx.x >> 3;
    int qt = blockIdx.x & 7;
    int qrow0 = g * NPG + qt * 64;

    wl[t] = 0.f; wl[t + 256] = 0.f;
    const float4* q4 = (const float4*)(q + (size_t)qrow0 * HD);
#pragma unroll
    for (int i = 0; i < 8; ++i) {
        int idx = t + 256 * i;
        *(float4*)&Ql[idx >> 5][(idx & 31) * 4] = q4[idx];
    }
    // prefetch K-tile 0 into registers
    float4 pf[8];
    {
        int node0 = g * NPG;
#pragma unroll
        for (int i = 0; i < 8; ++i) {
            int idx = t + 256 * i;      // d = idx>>4 (0..127), cq = idx&15
            pf[i] = *(const float4*)&kT[(size_t)(idx >> 4) * NN + node0 + (idx & 15) * 4];
        }
    }
    int cg = t & 15, rg = t >> 4;
    float p[8][4][4];    // raw scores, statically indexed (mt loop unrolled)

#pragma unroll
    for (int mt = 0; mt < 8; ++mt) {
        __syncthreads();                 // Kt consumers of prev tile done
#pragma unroll
        for (int i = 0; i < 8; ++i) {    // regs -> LDS
            int idx = t + 256 * i;
            *(float4*)&Kt[idx >> 4][(idx & 15) * 4] = pf[i];
        }
        __syncthreads();
        if (mt < 7) {                    // issue next tile's loads early
            int nn0 = g * NPG + (mt + 1) * 64;
#pragma unroll
            for (int i = 0; i < 8; ++i) {
                int idx = t + 256 * i;
                pf[i] = *(const float4*)&kT[(size_t)(idx >> 4) * NN + nn0 + (idx & 15) * 4];
            }
        }
#pragma unroll
        for (int r = 0; r < 4; ++r)
#pragma unroll
            for (int c = 0; c < 4; ++c) p[mt][r][c] = 0.f;
#pragma unroll 2
        for (int kk = 0; kk < 128; kk += 4) {
            float4 a0 = *(const float4*)&Ql[rg * 4 + 0][kk];
            float4 a1 = *(const float4*)&Ql[rg * 4 + 1][kk];
            float4 a2 = *(const float4*)&Ql[rg * 4 + 2][kk];
            float4 a3 = *(const float4*)&Ql[rg * 4 + 3][kk];
            float4 w0 = *(const float4*)&Kt[kk + 0][cg * 4];
            float4 w1 = *(const float4*)&Kt[kk + 1][cg * 4];
            float4 w2 = *(const float4*)&Kt[kk + 2][cg * 4];
            float4 w3 = *(const float4*)&Kt[kk + 3][cg * 4];
            PFMA(mt, 0, a0.x, w0) PFMA(mt, 0, a0.y, w1) PFMA(mt, 0, a0.z, w2) PFMA(mt, 0, a0.w, w3)
            PFMA(mt, 1, a1.x, w0) PFMA(mt, 1, a1.y, w1) PFMA(mt, 1, a1.z, w2) PFMA(mt, 1, a1.w, w3)
            PFMA(mt, 2, a2.x, w0) PFMA(mt, 2, a2.y, w1) PFMA(mt, 2, a2.z, w2) PFMA(mt, 2, a2.w, w3)
            PFMA(mt, 3, a3.x, w0) PFMA(mt, 3, a3.y, w1) PFMA(mt, 3, a3.z, w2) PFMA(mt, 3, a3.w, w3)
        }
    }

    // row max (post-hoc, over stored raw scores)
    float mrow[4], linv[4];
#pragma unroll
    for (int r = 0; r < 4; ++r) {
        float m = p[0][r][0];
#pragma unroll
        for (int mt = 0; mt < 8; ++mt)
#pragma unroll
            for (int c = 0; c < 4; ++c) m = fmaxf(m, p[mt][r][c]);
        m = fmaxf(m, __shfl_xor(m, 1));
        m = fmaxf(m, __shfl_xor(m, 2));
        m = fmaxf(m, __shfl_xor(m, 4));
        m = fmaxf(m, __shfl_xor(m, 8));
        mrow[r] = m;
    }
    // exponentiate in place
#pragma unroll
    for (int mt = 0; mt < 8; ++mt)
#pragma unroll
        for (int r = 0; r < 4; ++r)
#pragma unroll
            for (int c = 0; c < 4; ++c)
                p[mt][r][c] = __expf((p[mt][r][c] - mrow[r]) * RSQRT_H);
    // row sumexp -> 1/l
#pragma unroll
    for (int r = 0; r < 4; ++r) {
        float l = 0.f;
#pragma unroll
        for (int mt = 0; mt < 8; ++mt)
#pragma unroll
            for (int c = 0; c < 4; ++c) l += p[mt][r][c];
        l += __shfl_xor(l, 1);
        l += __shfl_xor(l, 2);
        l += __shfl_xor(l, 4);
        l += __shfl_xor(l, 8);
        linv[r] = 1.f / l;
    }
    // column sums of normalized attention
#pragma unroll
    for (int mt = 0; mt < 8; ++mt) {
#pragma unroll
        for (int c = 0; c < 4; ++c) {
            float pc = p[mt][0][c] * linv[0] + p[mt][1][c] * linv[1]
                     + p[mt][2][c] * linv[2] + p[mt][3][c] * linv[3];
            pc += __shfl_xor(pc, 16);
            pc += __shfl_xor(pc, 32);
            if ((t & 63) < 16) atomicAdd(&wl[mt * 64 + cg * 4 + c], pc);
        }
    }
    __syncthreads();
    float* wp = wpart + ((size_t)(g * 8 + qt)) * NPG;
    wp[t]       = wl[t]       * (1.f / NPG);
    wp[t + 256] = wl[t + 256] * (1.f / NPG);
}

// ---------------------------------------------------------------- pool + head
// u-partials: block (g,ch) sums 64 rows; w = sum of 8 qt slices. No atomics.
__global__ __launch_bounds__(128) void k_pool(
    const float* __restrict__ wpart, const float* __restrict__ h,
    float* __restrict__ upart)
{
    __shared__ float wloc[64];
    int b = blockIdx.x;
    int g = b >> 3, ch = b & 7;
    int t = threadIdx.x;
    if (t < 64) {
        float w = 0.f;
#pragma unroll
        for (int qt = 0; qt < 8; ++qt)
            w += wpart[((size_t)(g * 8 + qt)) * NPG + ch * 64 + t];
        wloc[t] = w;
    }
    __syncthreads();
    const float* hg = h + ((size_t)g * NPG + ch * 64) * HD;
    float u = 0.f;
#pragma unroll 4
    for (int m = 0; m < 64; ++m) u += wloc[m] * hg[m * HD + t];
    upart[(size_t)(ch * GG + g) * HD + t] = u;
}

__global__ __launch_bounds__(128) void k_head2(
    const float* __restrict__ upart,
    const float* __restrict__ Wv, const float* __restrict__ bv,
    const float* __restrict__ Wh1, const float* __restrict__ bh1,
    const float* __restrict__ Wh2, const float* __restrict__ bh2,
    float* __restrict__ out)
{
    __shared__ float ul[128];
    __shared__ float pl[128];
    __shared__ float r1l[64];
    int g = blockIdx.x, t = threadIdx.x;
    float ud = 0.f;
#pragma unroll
    for (int ch = 0; ch < 8; ++ch) ud += upart[(size_t)(ch * GG + g) * HD + t];
    ul[t] = ud;
    __syncthreads();
    float pv = bv[t];
    for (int d = 0; d < HD; ++d) pv += ul[d] * Wv[d * HD + t];
    pl[t] = pv;
    __syncthreads();
    if (t < 64) {
        float r1 = bh1[t];
        for (int d = 0; d < HD; ++d) r1 += pl[d] * Wh1[d * 64 + t];
        r1l[t] = fmaxf(r1, 0.f);
    }
    __syncthreads();
    if (t == 0) {
        float o = bh2[0];
        for (int j = 0; j < 64; ++j) o += r1l[j] * Wh2[j];
        out[g] = o;
    }
}

// ---------------------------------------------------------------- launch
extern "C" void kernel_launch(void* const* d_in, const int* in_sizes, int n_in,
                              void* d_out, int out_size, void* d_ws, size_t ws_size,
                              hipStream_t stream) {
    const float* x   = (const float*)d_in[0];
    const int* edge  = (const int*)d_in[1];
    // d_in[2] = batch (unused: batch = arange // 512 exactly)
    const float* W1  = (const float*)d_in[3];
    const float* b1  = (const float*)d_in[4];
    const float* W2  = (const float*)d_in[5];
    const float* b2  = (const float*)d_in[6];
    const float* Wq  = (const float*)d_in[7];
    const float* bq  = (const float*)d_in[8];
    const float* Wk  = (const float*)d_in[9];
    const float* bk  = (const float*)d_in[10];
    const float* Wv  = (const float*)d_in[11];
    const float* bv  = (const float*)d_in[12];
    const float* Wh1 = (const float*)d_in[13];
    const float* bh1 = (const float*)d_in[14];
    const float* Wh2 = (const float*)d_in[15];
    const float* bh2 = (const float*)d_in[16];
    float* out = (float*)d_out;

    int E = in_sizes[1] / 2;
    const int* src = edge;
    const int* dst = edge + E;

    // workspace layout (~51 MB):
    //  tbuf/qbuf [N*HD] | hbuf [N*HD] | kTb [HD*N] (early life: ELL int[N*64];
    //  late life: upart overlays its head after attn) | wpart | cursor
    float* tbuf = (float*)d_ws;                      // [N][128] (also qbuf)
    float* hbuf = tbuf + (size_t)NN * HD;            // [N][128]
    float* kTb  = hbuf + (size_t)NN * HD;            // [128][N]
    float* wpart = kTb + (size_t)NN * HD;            // [64*8][512]
    int* cursor = (int*)(wpart + GG * 8 * NPG);      // [N]
    int* ell    = (int*)kTb;                         // [N][64], dead before kTb born
    float* qbuf = tbuf;
    float* upart = kTb;                              // [8*64][128], kTb dead after attn

    int eb = (E + 255) / 256;
    dim3 ggrid(NN / 64, 2);

    // graph structure (ELL, no scan, no init kernel)
    hipMemsetAsync(cursor, 0, NN * sizeof(int), stream);
    k_fill<<<eb, 256, 0, stream>>>(src, dst, cursor, ell, E);

    // conv1
    k_gemm<<<ggrid, 256, 0, stream>>>(x, W1, tbuf, NN);
    k_agg<<<NN, 128, 0, stream>>>(tbuf, cursor, ell, b1, hbuf);
    // conv2
    k_gemm<<<ggrid, 256, 0, stream>>>(hbuf, W2, tbuf, NN);
    k_agg<<<NN, 128, 0, stream>>>(tbuf, cursor, ell, b2, hbuf);
    // q + kT in one pass (ell dead from here; kTb reuses its space)
    k_gemm_qk<<<ggrid, 256, 0, stream>>>(hbuf, Wq, bq, Wk, bk, qbuf, kTb, NN);
    // attention column weights (per-qt slices, no atomics)
    k_attn<<<GG * 8, 256, 0, stream>>>(qbuf, kTb, wpart);
    // pool partials + MLP head (upart overlays dead kTb)
    k_pool<<<GG * 8, 128, 0, stream>>>(wpart, hbuf, upart);
    k_head2<<<GG, 128, 0, stream>>>(upart, Wv, bv, Wh1, bh1, Wh2, bh2, out);
}

// Round 5
// 342.598 us; speedup vs baseline: 1.8376x; 1.1396x over previous
//
#include <hip/hip_runtime.h>
#include <hip/hip_fp16.h>
#include <hip/hip_bf16.h>

// Problem constants (fixed by the reference)
#define NN 32768      // nodes
#define GG 64         // graphs
#define NPG 512       // nodes per graph
#define HD 128        // feature/hidden width
#define MAXD 64       // ELL pad (mean degree 16, P(>64) ~ 1e-26)
#define RSQRT_H 0.08838834764831845f  // 1/sqrt(128)

// ---------------------------------------------------------------- ELL build
__global__ void k_fill(const int* __restrict__ src, const int* __restrict__ dst,
                       int* __restrict__ cursor, int* __restrict__ ell, int E) {
    int e = blockIdx.x * 256 + threadIdx.x;
    if (e < E) {
        int d = dst[e];
        int slot = atomicAdd(&cursor[d], 1);
        if (slot < MAXD) ell[d * MAXD + slot] = src[e];
    }
}

// ---------------------------------------------------------------- GEMM [M,128]@[128,128]
// 64x64 tile, 256 threads, 4x4 micro-tile. A row-major in LDS (pad 132),
// W k-major (pad 68). All hot-loop LDS reads are broadcast or 2-way (free).
#define FMA_ROW(r, av, wv) \
    acc[r][0] += (av)*(wv).x; acc[r][1] += (av)*(wv).y; \
    acc[r][2] += (av)*(wv).z; acc[r][3] += (av)*(wv).w;

// variant writing fp16 output (pre-aggregation t-matrices; agg gathers fp16)
__global__ __launch_bounds__(256) void k_gemm_h(
    const float* __restrict__ A, const float* __restrict__ W,
    __half* __restrict__ out, int M)
{
    __shared__ float Al[64][132];
    __shared__ float Wt[128][68];
    int t = threadIdx.x;
    int row0 = blockIdx.x * 64;
    int col0 = blockIdx.y * 64;

    const float4* A4 = (const float4*)(A + (size_t)row0 * HD);
#pragma unroll
    for (int i = 0; i < 8; ++i) {
        int idx = t + 256 * i;          // 2048 float4 = 64 rows x 32 kquads
        *(float4*)&Al[idx >> 5][(idx & 31) * 4] = A4[idx];
    }
    const float4* W4 = (const float4*)W;
#pragma unroll
    for (int i = 0; i < 8; ++i) {
        int idx = t + 256 * i;          // 2048 float4 = 128 k x 16 colquads
        int k = idx >> 4, cq = idx & 15;
        *(float4*)&Wt[k][cq * 4] = W4[k * 32 + (col0 >> 2) + cq];
    }
    __syncthreads();

    int cg = t & 15, rg = t >> 4;
    float acc[4][4] = {{0.f}};
#pragma unroll 2
    for (int kk = 0; kk < 128; kk += 4) {
        float4 a0 = *(const float4*)&Al[rg * 4 + 0][kk];
        float4 a1 = *(const float4*)&Al[rg * 4 + 1][kk];
        float4 a2 = *(const float4*)&Al[rg * 4 + 2][kk];
        float4 a3 = *(const float4*)&Al[rg * 4 + 3][kk];
        float4 w0 = *(const float4*)&Wt[kk + 0][cg * 4];
        float4 w1 = *(const float4*)&Wt[kk + 1][cg * 4];
        float4 w2 = *(const float4*)&Wt[kk + 2][cg * 4];
        float4 w3 = *(const float4*)&Wt[kk + 3][cg * 4];
        FMA_ROW(0, a0.x, w0) FMA_ROW(0, a0.y, w1) FMA_ROW(0, a0.z, w2) FMA_ROW(0, a0.w, w3)
        FMA_ROW(1, a1.x, w0) FMA_ROW(1, a1.y, w1) FMA_ROW(1, a1.z, w2) FMA_ROW(1, a1.w, w3)
        FMA_ROW(2, a2.x, w0) FMA_ROW(2, a2.y, w1) FMA_ROW(2, a2.z, w2) FMA_ROW(2, a2.w, w3)
        FMA_ROW(3, a3.x, w0) FMA_ROW(3, a3.y, w1) FMA_ROW(3, a3.z, w2) FMA_ROW(3, a3.w, w3)
    }
#pragma unroll
    for (int r = 0; r < 4; ++r) {
        int row = row0 + rg * 4 + r;
        __half2 p01, p23;
        p01.x = __float2half(acc[r][0]); p01.y = __float2half(acc[r][1]);
        p23.x = __float2half(acc[r][2]); p23.y = __float2half(acc[r][3]);
        __half2* o = (__half2*)&out[(size_t)row * HD + col0 + cg * 4];
        o[0] = p01; o[1] = p23;
    }
}

// Fused Q/K projection: stage A-tile once, two K-loops. q written normal,
// k written transposed [HD][NN] via LDS restage (coalesced). fp32 out.
__global__ __launch_bounds__(256) void k_gemm_qk(
    const float* __restrict__ A,
    const float* __restrict__ Wq, const float* __restrict__ bq,
    const float* __restrict__ Wk, const float* __restrict__ bk,
    float* __restrict__ qout, float* __restrict__ kTout, int M)
{
    __shared__ float Al[64][132];
    __shared__ float Wt[128][68];
    int t = threadIdx.x;
    int row0 = blockIdx.x * 64;
    int col0 = blockIdx.y * 64;
    int cg = t & 15, rg = t >> 4;

    const float4* A4 = (const float4*)(A + (size_t)row0 * HD);
#pragma unroll
    for (int i = 0; i < 8; ++i) {
        int idx = t + 256 * i;
        *(float4*)&Al[idx >> 5][(idx & 31) * 4] = A4[idx];
    }
    const float4* Wq4 = (const float4*)Wq;
#pragma unroll
    for (int i = 0; i < 8; ++i) {
        int idx = t + 256 * i;
        int k = idx >> 4, cq = idx & 15;
        *(float4*)&Wt[k][cq * 4] = Wq4[k * 32 + (col0 >> 2) + cq];
    }
    __syncthreads();

    {
        float acc[4][4] = {{0.f}};
#pragma unroll 2
        for (int kk = 0; kk < 128; kk += 4) {
            float4 a0 = *(const float4*)&Al[rg * 4 + 0][kk];
            float4 a1 = *(const float4*)&Al[rg * 4 + 1][kk];
            float4 a2 = *(const float4*)&Al[rg * 4 + 2][kk];
            float4 a3 = *(const float4*)&Al[rg * 4 + 3][kk];
            float4 w0 = *(const float4*)&Wt[kk + 0][cg * 4];
            float4 w1 = *(const float4*)&Wt[kk + 1][cg * 4];
            float4 w2 = *(const float4*)&Wt[kk + 2][cg * 4];
            float4 w3 = *(const float4*)&Wt[kk + 3][cg * 4];
            FMA_ROW(0, a0.x, w0) FMA_ROW(0, a0.y, w1) FMA_ROW(0, a0.z, w2) FMA_ROW(0, a0.w, w3)
            FMA_ROW(1, a1.x, w0) FMA_ROW(1, a1.y, w1) FMA_ROW(1, a1.z, w2) FMA_ROW(1, a1.w, w3)
            FMA_ROW(2, a2.x, w0) FMA_ROW(2, a2.y, w1) FMA_ROW(2, a2.z, w2) FMA_ROW(2, a2.w, w3)
            FMA_ROW(3, a3.x, w0) FMA_ROW(3, a3.y, w1) FMA_ROW(3, a3.z, w2) FMA_ROW(3, a3.w, w3)
        }
        int c = col0 + cg * 4;
        float4 bqv = make_float4(bq[c], bq[c+1], bq[c+2], bq[c+3]);
#pragma unroll
        for (int r = 0; r < 4; ++r) {
            int row = row0 + rg * 4 + r;
            *(float4*)&qout[(size_t)row * HD + c] =
                make_float4(acc[r][0] + bqv.x, acc[r][1] + bqv.y,
                            acc[r][2] + bqv.z, acc[r][3] + bqv.w);
        }
    }
    __syncthreads();                     // everyone done reading Wt
    const float4* Wk4 = (const float4*)Wk;
#pragma unroll
    for (int i = 0; i < 8; ++i) {
        int idx = t + 256 * i;
        int k = idx >> 4, cq = idx & 15;
        *(float4*)&Wt[k][cq * 4] = Wk4[k * 32 + (col0 >> 2) + cq];
    }
    __syncthreads();

    float acc[4][4] = {{0.f}};
#pragma unroll 2
    for (int kk = 0; kk < 128; kk += 4) {
        float4 a0 = *(const float4*)&Al[rg * 4 + 0][kk];
        float4 a1 = *(const float4*)&Al[rg * 4 + 1][kk];
        float4 a2 = *(const float4*)&Al[rg * 4 + 2][kk];
        float4 a3 = *(const float4*)&Al[rg * 4 + 3][kk];
        float4 w0 = *(const float4*)&Wt[kk + 0][cg * 4];
        float4 w1 = *(const float4*)&Wt[kk + 1][cg * 4];
        float4 w2 = *(const float4*)&Wt[kk + 2][cg * 4];
        float4 w3 = *(const float4*)&Wt[kk + 3][cg * 4];
        FMA_ROW(0, a0.x, w0) FMA_ROW(0, a0.y, w1) FMA_ROW(0, a0.z, w2) FMA_ROW(0, a0.w, w3)
        FMA_ROW(1, a1.x, w0) FMA_ROW(1, a1.y, w1) FMA_ROW(1, a1.z, w2) FMA_ROW(1, a1.w, w3)
        FMA_ROW(2, a2.x, w0) FMA_ROW(2, a2.y, w1) FMA_ROW(2, a2.z, w2) FMA_ROW(2, a2.w, w3)
        FMA_ROW(3, a3.x, w0) FMA_ROW(3, a3.y, w1) FMA_ROW(3, a3.z, w2) FMA_ROW(3, a3.w, w3)
    }
    // transpose epilogue through LDS (Al is dead)
    __syncthreads();
    float* Sl = &Al[0][0];               // 64x64 tile, stride 68
#pragma unroll
    for (int r = 0; r < 4; ++r)
        *(float4*)&Sl[(rg * 4 + r) * 68 + cg * 4] =
            make_float4(acc[r][0], acc[r][1], acc[r][2], acc[r][3]);
    __syncthreads();
#pragma unroll
    for (int i = 0; i < 4; ++i) {
        int idx = t + 256 * i;           // 1024 float4 = 64 cols x 16 rowquads
        int c = idx >> 4, rq = idx & 15;
        float b = bk[col0 + c];
        float4 o = make_float4(Sl[(rq * 4 + 0) * 68 + c] + b,
                               Sl[(rq * 4 + 1) * 68 + c] + b,
                               Sl[(rq * 4 + 2) * 68 + c] + b,
                               Sl[(rq * 4 + 3) * 68 + c] + b);
        *(float4*)&kTout[(size_t)(col0 + c) * M + row0 + rq * 4] = o;
    }
}

// ---------------------------------------------------------------- aggregation
// one 64-lane wave per node (4 nodes / 256-thread block); fp16 gather rows
// (256B coalesced per row), fp32 accumulate, dinv on the fly from cursor.
__global__ __launch_bounds__(256) void k_agg(
    const __half* __restrict__ tmat, const int* __restrict__ cursor,
    const int* __restrict__ ell, const float* __restrict__ bias,
    float* __restrict__ hout)
{
    int t = threadIdx.x;
    int i = blockIdx.x * 4 + (t >> 6);   // node
    int lane = t & 63;                   // feature pair index
    int cnt = min(cursor[i], MAXD);
    float di = rsqrtf((float)(cnt + 1));
    float2 sv = __half22float2(((const __half2*)(tmat + (size_t)i * HD))[lane]);
    float acc0 = sv.x * (di * di);
    float acc1 = sv.y * (di * di);
    const int* row = ell + (size_t)i * MAXD;
    int e = 0;
    for (; e + 2 <= cnt; e += 2) {       // 2-edge ILP unroll
        int s0 = row[e], s1 = row[e + 1];
        float w0 = rsqrtf((float)(min(cursor[s0], MAXD) + 1)) * di;
        float w1 = rsqrtf((float)(min(cursor[s1], MAXD) + 1)) * di;
        float2 v0 = __half22float2(((const __half2*)(tmat + (size_t)s0 * HD))[lane]);
        float2 v1 = __half22float2(((const __half2*)(tmat + (size_t)s1 * HD))[lane]);
        acc0 += v0.x * w0 + v1.x * w1;
        acc1 += v0.y * w0 + v1.y * w1;
    }
    if (e < cnt) {
        int s0 = row[e];
        float w0 = rsqrtf((float)(min(cursor[s0], MAXD) + 1)) * di;
        float2 v0 = __half22float2(((const __half2*)(tmat + (size_t)s0 * HD))[lane]);
        acc0 += v0.x * w0;
        acc1 += v0.y * w0;
    }
    int f = lane * 2;
    *(float2*)&hout[(size_t)i * HD + f] =
        make_float2(fmaxf(acc0 + bias[f], 0.f), fmaxf(acc1 + bias[f + 1], 0.f));
}

// ---------------------------------------------------------------- attention
// Single pass, S in registers (2 blocks/CU -> regs free). Direct global->LDS
// staging per tile (NO register prefetch: round-4's pf[] caused scratch
// spills, WRITE_SIZE 1MB -> 118MB, dur +15us). Per-(g,qt) wpart slices out.
#define PFMA(mt, r, av, wv) \
    p[mt][r][0] += (av)*(wv).x; p[mt][r][1] += (av)*(wv).y; \
    p[mt][r][2] += (av)*(wv).z; p[mt][r][3] += (av)*(wv).w;

__global__ __launch_bounds__(256, 2) void k_attn(
    const float* __restrict__ q,    // [N][128]
    const float* __restrict__ kT,   // [128][N]
    float* __restrict__ wpart)      // [64][8][512]
{
    __shared__ float Ql[64][132];
    __shared__ float Kt[128][68];
    __shared__ float wl[512];
    int t = threadIdx.x;
    int g = blockIdx.x >> 3;
    int qt = blockIdx.x & 7;
    int qrow0 = g * NPG + qt * 64;

    wl[t] = 0.f; wl[t + 256] = 0.f;
    const float4* q4 = (const float4*)(q + (size_t)qrow0 * HD);
#pragma unroll
    for (int i = 0; i < 8; ++i) {
        int idx = t + 256 * i;
        *(float4*)&Ql[idx >> 5][(idx & 31) * 4] = q4[idx];
    }
    int cg = t & 15, rg = t >> 4;
    float p[8][4][4];    // raw scores, statically indexed (mt loop unrolled)

#pragma unroll
    for (int mt = 0; mt < 8; ++mt) {
        __syncthreads();                 // Kt consumers of prev tile done
        int node0 = g * NPG + mt * 64;
#pragma unroll
        for (int i = 0; i < 8; ++i) {
            int idx = t + 256 * i;      // 2048 float4 = 128 d x 16 colquads
            int d = idx >> 4, cq = idx & 15;
            *(float4*)&Kt[d][cq * 4] =
                *(const float4*)&kT[(size_t)d * NN + node0 + cq * 4];
        }
        __syncthreads();
#pragma unroll
        for (int r = 0; r < 4; ++r)
#pragma unroll
            for (int c = 0; c < 4; ++c) p[mt][r][c] = 0.f;
#pragma unroll 2
        for (int kk = 0; kk < 128; kk += 4) {
            float4 a0 = *(const float4*)&Ql[rg * 4 + 0][kk];
            float4 a1 = *(const float4*)&Ql[rg * 4 + 1][kk];
            float4 a2 = *(const float4*)&Ql[rg * 4 + 2][kk];
            float4 a3 = *(const float4*)&Ql[rg * 4 + 3][kk];
            float4 w0 = *(const float4*)&Kt[kk + 0][cg * 4];
            float4 w1 = *(const float4*)&Kt[kk + 1][cg * 4];
            float4 w2 = *(const float4*)&Kt[kk + 2][cg * 4];
            float4 w3 = *(const float4*)&Kt[kk + 3][cg * 4];
            PFMA(mt, 0, a0.x, w0) PFMA(mt, 0, a0.y, w1) PFMA(mt, 0, a0.z, w2) PFMA(mt, 0, a0.w, w3)
            PFMA(mt, 1, a1.x, w0) PFMA(mt, 1, a1.y, w1) PFMA(mt, 1, a1.z, w2) PFMA(mt, 1, a1.w, w3)
            PFMA(mt, 2, a2.x, w0) PFMA(mt, 2, a2.y, w1) PFMA(mt, 2, a2.z, w2) PFMA(mt, 2, a2.w, w3)
            PFMA(mt, 3, a3.x, w0) PFMA(mt, 3, a3.y, w1) PFMA(mt, 3, a3.z, w2) PFMA(mt, 3, a3.w, w3)
        }
    }

    // row max (post-hoc, over stored raw scores)
    float mrow[4], linv[4];
#pragma unroll
    for (int r = 0; r < 4; ++r) {
        float m = p[0][r][0];
#pragma unroll
        for (int mt = 0; mt < 8; ++mt)
#pragma unroll
            for (int c = 0; c < 4; ++c) m = fmaxf(m, p[mt][r][c]);
        m = fmaxf(m, __shfl_xor(m, 1));
        m = fmaxf(m, __shfl_xor(m, 2));
        m = fmaxf(m, __shfl_xor(m, 4));
        m = fmaxf(m, __shfl_xor(m, 8));
        mrow[r] = m;
    }
    // exponentiate in place
#pragma unroll
    for (int mt = 0; mt < 8; ++mt)
#pragma unroll
        for (int r = 0; r < 4; ++r)
#pragma unroll
            for (int c = 0; c < 4; ++c)
                p[mt][r][c] = __expf((p[mt][r][c] - mrow[r]) * RSQRT_H);
    // row sumexp -> 1/l
#pragma unroll
    for (int r = 0; r < 4; ++r) {
        float l = 0.f;
#pragma unroll
        for (int mt = 0; mt < 8; ++mt)
#pragma unroll
            for (int c = 0; c < 4; ++c) l += p[mt][r][c];
        l += __shfl_xor(l, 1);
        l += __shfl_xor(l, 2);
        l += __shfl_xor(l, 4);
        l += __shfl_xor(l, 8);
        linv[r] = 1.f / l;
    }
    // column sums of normalized attention
#pragma unroll
    for (int mt = 0; mt < 8; ++mt) {
#pragma unroll
        for (int c = 0; c < 4; ++c) {
            float pc = p[mt][0][c] * linv[0] + p[mt][1][c] * linv[1]
                     + p[mt][2][c] * linv[2] + p[mt][3][c] * linv[3];
            pc += __shfl_xor(pc, 16);
            pc += __shfl_xor(pc, 32);
            if ((t & 63) < 16) atomicAdd(&wl[mt * 64 + cg * 4 + c], pc);
        }
    }
    __syncthreads();
    float* wp = wpart + ((size_t)(g * 8 + qt)) * NPG;
    wp[t]       = wl[t]       * (1.f / NPG);
    wp[t + 256] = wl[t + 256] * (1.f / NPG);
}

// ---------------------------------------------------------------- pool + head
// u-partials: block (g,ch) sums 64 rows; w = sum of 8 qt slices. No atomics.
__global__ __launch_bounds__(128) void k_pool(
    const float* __restrict__ wpart, const float* __restrict__ h,
    float* __restrict__ upart)
{
    __shared__ float wloc[64];
    int b = blockIdx.x;
    int g = b >> 3, ch = b & 7;
    int t = threadIdx.x;
    if (t < 64) {
        float w = 0.f;
#pragma unroll
        for (int qt = 0; qt < 8; ++qt)
            w += wpart[((size_t)(g * 8 + qt)) * NPG + ch * 64 + t];
        wloc[t] = w;
    }
    __syncthreads();
    const float* hg = h + ((size_t)g * NPG + ch * 64) * HD;
    float u = 0.f;
#pragma unroll 4
    for (int m = 0; m < 64; ++m) u += wloc[m] * hg[m * HD + t];
    upart[(size_t)(ch * GG + g) * HD + t] = u;
}

__global__ __launch_bounds__(128) void k_head2(
    const float* __restrict__ upart,
    const float* __restrict__ Wv, const float* __restrict__ bv,
    const float* __restrict__ Wh1, const float* __restrict__ bh1,
    const float* __restrict__ Wh2, const float* __restrict__ bh2,
    float* __restrict__ out)
{
    __shared__ float ul[128];
    __shared__ float pl[128];
    __shared__ float r1l[64];
    int g = blockIdx.x, t = threadIdx.x;
    float ud = 0.f;
#pragma unroll
    for (int ch = 0; ch < 8; ++ch) ud += upart[(size_t)(ch * GG + g) * HD + t];
    ul[t] = ud;
    __syncthreads();
    float pv = bv[t];
    for (int d = 0; d < HD; ++d) pv += ul[d] * Wv[d * HD + t];
    pl[t] = pv;
    __syncthreads();
    if (t < 64) {
        float r1 = bh1[t];
        for (int d = 0; d < HD; ++d) r1 += pl[d] * Wh1[d * 64 + t];
        r1l[t] = fmaxf(r1, 0.f);
    }
    __syncthreads();
    if (t == 0) {
        float o = bh2[0];
        for (int j = 0; j < 64; ++j) o += r1l[j] * Wh2[j];
        out[g] = o;
    }
}

// ---------------------------------------------------------------- launch
extern "C" void kernel_launch(void* const* d_in, const int* in_sizes, int n_in,
                              void* d_out, int out_size, void* d_ws, size_t ws_size,
                              hipStream_t stream) {
    const float* x   = (const float*)d_in[0];
    const int* edge  = (const int*)d_in[1];
    // d_in[2] = batch (unused: batch = arange // 512 exactly)
    const float* W1  = (const float*)d_in[3];
    const float* b1  = (const float*)d_in[4];
    const float* W2  = (const float*)d_in[5];
    const float* b2  = (const float*)d_in[6];
    const float* Wq  = (const float*)d_in[7];
    const float* bq  = (const float*)d_in[8];
    const float* Wk  = (const float*)d_in[9];
    const float* bk  = (const float*)d_in[10];
    const float* Wv  = (const float*)d_in[11];
    const float* bv  = (const float*)d_in[12];
    const float* Wh1 = (const float*)d_in[13];
    const float* bh1 = (const float*)d_in[14];
    const float* Wh2 = (const float*)d_in[15];
    const float* bh2 = (const float*)d_in[16];
    float* out = (float*)d_out;

    int E = in_sizes[1] / 2;
    const int* src = edge;
    const int* dst = edge + E;

    // workspace layout (~51 MB):
    //  tbuf region: fp16 t-matrix early, fp32 qbuf later | hbuf | kTb
    //  (early life: ELL int[N*64]; late life: upart) | wpart | cursor
    float* tbuf = (float*)d_ws;                      // region [N*128] fp32
    float* hbuf = tbuf + (size_t)NN * HD;            // [N][128]
    float* kTb  = hbuf + (size_t)NN * HD;            // [128][N]
    float* wpart = kTb + (size_t)NN * HD;            // [64*8][512]
    int* cursor = (int*)(wpart + GG * 8 * NPG);      // [N]
    int* ell    = (int*)kTb;                         // [N][64], dead before kTb born
    __half* tmat = (__half*)tbuf;                    // [N][128] fp16 (8MB)
    float* qbuf = tbuf;                              // [N][128] fp32, after aggs
    float* upart = kTb;                              // [8*64][128], kTb dead after attn

    int eb = (E + 255) / 256;
    dim3 ggrid(NN / 64, 2);

    // graph structure (ELL, no scan, no init kernel)
    hipMemsetAsync(cursor, 0, NN * sizeof(int), stream);
    k_fill<<<eb, 256, 0, stream>>>(src, dst, cursor, ell, E);

    // conv1
    k_gemm_h<<<ggrid, 256, 0, stream>>>(x, W1, tmat, NN);
    k_agg<<<NN / 4, 256, 0, stream>>>(tmat, cursor, ell, b1, hbuf);
    // conv2
    k_gemm_h<<<ggrid, 256, 0, stream>>>(hbuf, W2, tmat, NN);
    k_agg<<<NN / 4, 256, 0, stream>>>(tmat, cursor, ell, b2, hbuf);
    // q + kT in one pass (ell dead from here; kTb reuses its space)
    k_gemm_qk<<<ggrid, 256, 0, stream>>>(hbuf, Wq, bq, Wk, bk, qbuf, kTb, NN);
    // attention column weights (per-qt slices, no atomics)
    k_attn<<<GG * 8, 256, 0, stream>>>(qbuf, kTb, wpart);
    // pool partials + MLP head (upart overlays dead kTb)
    k_pool<<<GG * 8, 128, 0, stream>>>(wpart, hbuf, upart);
    k_head2<<<GG, 128, 0, stream>>>(upart, Wv, bv, Wh1, bh1, Wh2, bh2, out);
}

// Round 6
// 297.345 us; speedup vs baseline: 2.1173x; 1.1522x over previous
//
#include <hip/hip_runtime.h>
#include <hip/hip_fp16.h>
#include <hip/hip_bf16.h>

// Problem constants (fixed by the reference)
#define NN 32768      // nodes
#define GG 64         // graphs
#define NPG 512       // nodes per graph
#define HD 128        // feature/hidden width
#define MAXD 64       // ELL pad (mean degree 16, P(>64) ~ 1e-26)
#define RSQRT_H 0.08838834764831845f  // 1/sqrt(128)

typedef _Float16 f16;
typedef __attribute__((ext_vector_type(8))) _Float16 f16x8;
typedef __attribute__((ext_vector_type(4))) float f32x4;

// ---------------------------------------------------------------- ELL build
__global__ void k_fill(const int* __restrict__ src, const int* __restrict__ dst,
                       int* __restrict__ cursor, int* __restrict__ ell, int E) {
    int e = blockIdx.x * 256 + threadIdx.x;
    if (e < E) {
        int d = dst[e];
        int slot = atomicAdd(&cursor[d], 1);
        if (slot < MAXD) ell[d * MAXD + slot] = src[e];
    }
}

// ---------------------------------------------------------------- GEMM [M,128]@[128,128]
// 64x64 tile, 256 threads, 4x4 micro-tile. A row-major in LDS (pad 132),
// W k-major (pad 68). All hot-loop LDS reads are broadcast or 2-way (free).
#define FMA_ROW(r, av, wv) \
    acc[r][0] += (av)*(wv).x; acc[r][1] += (av)*(wv).y; \
    acc[r][2] += (av)*(wv).z; acc[r][3] += (av)*(wv).w;

// variant writing fp16 output (pre-aggregation t-matrices; agg gathers fp16)
__global__ __launch_bounds__(256) void k_gemm_h(
    const float* __restrict__ A, const float* __restrict__ W,
    __half* __restrict__ out, int M)
{
    __shared__ float Al[64][132];
    __shared__ float Wt[128][68];
    int t = threadIdx.x;
    int row0 = blockIdx.x * 64;
    int col0 = blockIdx.y * 64;

    const float4* A4 = (const float4*)(A + (size_t)row0 * HD);
#pragma unroll
    for (int i = 0; i < 8; ++i) {
        int idx = t + 256 * i;          // 2048 float4 = 64 rows x 32 kquads
        *(float4*)&Al[idx >> 5][(idx & 31) * 4] = A4[idx];
    }
    const float4* W4 = (const float4*)W;
#pragma unroll
    for (int i = 0; i < 8; ++i) {
        int idx = t + 256 * i;          // 2048 float4 = 128 k x 16 colquads
        int k = idx >> 4, cq = idx & 15;
        *(float4*)&Wt[k][cq * 4] = W4[k * 32 + (col0 >> 2) + cq];
    }
    __syncthreads();

    int cg = t & 15, rg = t >> 4;
    float acc[4][4] = {{0.f}};
#pragma unroll 2
    for (int kk = 0; kk < 128; kk += 4) {
        float4 a0 = *(const float4*)&Al[rg * 4 + 0][kk];
        float4 a1 = *(const float4*)&Al[rg * 4 + 1][kk];
        float4 a2 = *(const float4*)&Al[rg * 4 + 2][kk];
        float4 a3 = *(const float4*)&Al[rg * 4 + 3][kk];
        float4 w0 = *(const float4*)&Wt[kk + 0][cg * 4];
        float4 w1 = *(const float4*)&Wt[kk + 1][cg * 4];
        float4 w2 = *(const float4*)&Wt[kk + 2][cg * 4];
        float4 w3 = *(const float4*)&Wt[kk + 3][cg * 4];
        FMA_ROW(0, a0.x, w0) FMA_ROW(0, a0.y, w1) FMA_ROW(0, a0.z, w2) FMA_ROW(0, a0.w, w3)
        FMA_ROW(1, a1.x, w0) FMA_ROW(1, a1.y, w1) FMA_ROW(1, a1.z, w2) FMA_ROW(1, a1.w, w3)
        FMA_ROW(2, a2.x, w0) FMA_ROW(2, a2.y, w1) FMA_ROW(2, a2.z, w2) FMA_ROW(2, a2.w, w3)
        FMA_ROW(3, a3.x, w0) FMA_ROW(3, a3.y, w1) FMA_ROW(3, a3.z, w2) FMA_ROW(3, a3.w, w3)
    }
#pragma unroll
    for (int r = 0; r < 4; ++r) {
        int row = row0 + rg * 4 + r;
        __half2 p01, p23;
        p01.x = __float2half(acc[r][0]); p01.y = __float2half(acc[r][1]);
        p23.x = __float2half(acc[r][2]); p23.y = __float2half(acc[r][3]);
        __half2* o = (__half2*)&out[(size_t)row * HD + col0 + cg * 4];
        o[0] = p01; o[1] = p23;
    }
}

// Fused Q/K projection: stage A-tile once, two K-loops. Both q and k written
// fp16 ROW-MAJOR (+bias): MFMA attention consumes K rows directly, so the
// transpose epilogue is gone.
__global__ __launch_bounds__(256) void k_gemm_qk(
    const float* __restrict__ A,
    const float* __restrict__ Wq, const float* __restrict__ bq,
    const float* __restrict__ Wk, const float* __restrict__ bk,
    __half* __restrict__ qout, __half* __restrict__ kout)
{
    __shared__ float Al[64][132];
    __shared__ float Wt[128][68];
    int t = threadIdx.x;
    int row0 = blockIdx.x * 64;
    int col0 = blockIdx.y * 64;
    int cg = t & 15, rg = t >> 4;

    const float4* A4 = (const float4*)(A + (size_t)row0 * HD);
#pragma unroll
    for (int i = 0; i < 8; ++i) {
        int idx = t + 256 * i;
        *(float4*)&Al[idx >> 5][(idx & 31) * 4] = A4[idx];
    }
    const float4* Wq4 = (const float4*)Wq;
#pragma unroll
    for (int i = 0; i < 8; ++i) {
        int idx = t + 256 * i;
        int k = idx >> 4, cq = idx & 15;
        *(float4*)&Wt[k][cq * 4] = Wq4[k * 32 + (col0 >> 2) + cq];
    }
    __syncthreads();

    {
        float acc[4][4] = {{0.f}};
#pragma unroll 2
        for (int kk = 0; kk < 128; kk += 4) {
            float4 a0 = *(const float4*)&Al[rg * 4 + 0][kk];
            float4 a1 = *(const float4*)&Al[rg * 4 + 1][kk];
            float4 a2 = *(const float4*)&Al[rg * 4 + 2][kk];
            float4 a3 = *(const float4*)&Al[rg * 4 + 3][kk];
            float4 w0 = *(const float4*)&Wt[kk + 0][cg * 4];
            float4 w1 = *(const float4*)&Wt[kk + 1][cg * 4];
            float4 w2 = *(const float4*)&Wt[kk + 2][cg * 4];
            float4 w3 = *(const float4*)&Wt[kk + 3][cg * 4];
            FMA_ROW(0, a0.x, w0) FMA_ROW(0, a0.y, w1) FMA_ROW(0, a0.z, w2) FMA_ROW(0, a0.w, w3)
            FMA_ROW(1, a1.x, w0) FMA_ROW(1, a1.y, w1) FMA_ROW(1, a1.z, w2) FMA_ROW(1, a1.w, w3)
            FMA_ROW(2, a2.x, w0) FMA_ROW(2, a2.y, w1) FMA_ROW(2, a2.z, w2) FMA_ROW(2, a2.w, w3)
            FMA_ROW(3, a3.x, w0) FMA_ROW(3, a3.y, w1) FMA_ROW(3, a3.z, w2) FMA_ROW(3, a3.w, w3)
        }
        int c = col0 + cg * 4;
        float b0 = bq[c], b1 = bq[c+1], b2 = bq[c+2], b3 = bq[c+3];
#pragma unroll
        for (int r = 0; r < 4; ++r) {
            int row = row0 + rg * 4 + r;
            __half2 p01, p23;
            p01.x = __float2half(acc[r][0] + b0); p01.y = __float2half(acc[r][1] + b1);
            p23.x = __float2half(acc[r][2] + b2); p23.y = __float2half(acc[r][3] + b3);
            __half2* o = (__half2*)&qout[(size_t)row * HD + c];
            o[0] = p01; o[1] = p23;
        }
    }
    __syncthreads();                     // everyone done reading Wt
    const float4* Wk4 = (const float4*)Wk;
#pragma unroll
    for (int i = 0; i < 8; ++i) {
        int idx = t + 256 * i;
        int k = idx >> 4, cq = idx & 15;
        *(float4*)&Wt[k][cq * 4] = Wk4[k * 32 + (col0 >> 2) + cq];
    }
    __syncthreads();

    float acc[4][4] = {{0.f}};
#pragma unroll 2
    for (int kk = 0; kk < 128; kk += 4) {
        float4 a0 = *(const float4*)&Al[rg * 4 + 0][kk];
        float4 a1 = *(const float4*)&Al[rg * 4 + 1][kk];
        float4 a2 = *(const float4*)&Al[rg * 4 + 2][kk];
        float4 a3 = *(const float4*)&Al[rg * 4 + 3][kk];
        float4 w0 = *(const float4*)&Wt[kk + 0][cg * 4];
        float4 w1 = *(const float4*)&Wt[kk + 1][cg * 4];
        float4 w2 = *(const float4*)&Wt[kk + 2][cg * 4];
        float4 w3 = *(const float4*)&Wt[kk + 3][cg * 4];
        FMA_ROW(0, a0.x, w0) FMA_ROW(0, a0.y, w1) FMA_ROW(0, a0.z, w2) FMA_ROW(0, a0.w, w3)
        FMA_ROW(1, a1.x, w0) FMA_ROW(1, a1.y, w1) FMA_ROW(1, a1.z, w2) FMA_ROW(1, a1.w, w3)
        FMA_ROW(2, a2.x, w0) FMA_ROW(2, a2.y, w1) FMA_ROW(2, a2.z, w2) FMA_ROW(2, a2.w, w3)
        FMA_ROW(3, a3.x, w0) FMA_ROW(3, a3.y, w1) FMA_ROW(3, a3.z, w2) FMA_ROW(3, a3.w, w3)
    }
    {
        int c = col0 + cg * 4;
        float b0 = bk[c], b1 = bk[c+1], b2 = bk[c+2], b3 = bk[c+3];
#pragma unroll
        for (int r = 0; r < 4; ++r) {
            int row = row0 + rg * 4 + r;
            __half2 p01, p23;
            p01.x = __float2half(acc[r][0] + b0); p01.y = __float2half(acc[r][1] + b1);
            p23.x = __float2half(acc[r][2] + b2); p23.y = __float2half(acc[r][3] + b3);
            __half2* o = (__half2*)&kout[(size_t)row * HD + c];
            o[0] = p01; o[1] = p23;
        }
    }
}

// ---------------------------------------------------------------- aggregation
// one 64-lane wave per node (4 nodes / 256-thread block); fp16 gather rows
// (256B coalesced per row), fp32 accumulate, dinv on the fly from cursor.
__global__ __launch_bounds__(256) void k_agg(
    const __half* __restrict__ tmat, const int* __restrict__ cursor,
    const int* __restrict__ ell, const float* __restrict__ bias,
    float* __restrict__ hout)
{
    int t = threadIdx.x;
    int i = blockIdx.x * 4 + (t >> 6);   // node
    int lane = t & 63;                   // feature pair index
    int cnt = min(cursor[i], MAXD);
    float di = rsqrtf((float)(cnt + 1));
    float2 sv = __half22float2(((const __half2*)(tmat + (size_t)i * HD))[lane]);
    float acc0 = sv.x * (di * di);
    float acc1 = sv.y * (di * di);
    const int* row = ell + (size_t)i * MAXD;
    int e = 0;
    for (; e + 2 <= cnt; e += 2) {       // 2-edge ILP unroll
        int s0 = row[e], s1 = row[e + 1];
        float w0 = rsqrtf((float)(min(cursor[s0], MAXD) + 1)) * di;
        float w1 = rsqrtf((float)(min(cursor[s1], MAXD) + 1)) * di;
        float2 v0 = __half22float2(((const __half2*)(tmat + (size_t)s0 * HD))[lane]);
        float2 v1 = __half22float2(((const __half2*)(tmat + (size_t)s1 * HD))[lane]);
        acc0 += v0.x * w0 + v1.x * w1;
        acc1 += v0.y * w0 + v1.y * w1;
    }
    if (e < cnt) {
        int s0 = row[e];
        float w0 = rsqrtf((float)(min(cursor[s0], MAXD) + 1)) * di;
        float2 v0 = __half22float2(((const __half2*)(tmat + (size_t)s0 * HD))[lane]);
        acc0 += v0.x * w0;
        acc1 += v0.y * w0;
    }
    int f = lane * 2;
    *(float2*)&hout[(size_t)i * HD + f] =
        make_float2(fmaxf(acc0 + bias[f], 0.f), fmaxf(acc1 + bias[f + 1], 0.f));
}

// ---------------------------------------------------------------- attention
// MFMA QK^T (fp16 in, fp32 acc). Per block: 4 waves, wave w owns q-rows
// [16w,16w+16) of a 64-row q-tile; S strip (16x512) lives in 32 f32x4 accs.
// Q frags in regs (loaded once); K tile staged in LDS [64][136] fp16 (pad 8
// -> uniform bank spread for ds_read_b128 frags). Fragment layouts per
// cdna4 docs: A/B lane l -> row/col l&15, k = (l>>4)*8+j; C/D col=lane&15,
// row=(lane>>4)*4+reg (m89-verified). Softmax reductions isomorphic to the
// old VALU kernel. No register prefetch (round-4 spill lesson).
__global__ __launch_bounds__(256, 2) void k_attn(
    const __half* __restrict__ qh,  // [N][128] fp16
    const __half* __restrict__ kh,  // [N][128] fp16
    float* __restrict__ wpart)      // [64*8][512]
{
    __shared__ f16 Kl[64][136];
    __shared__ float wlp[4][512];
    int t = threadIdx.x;
    int g = blockIdx.x >> 3;
    int qt = blockIdx.x & 7;
    int w = t >> 6, lane = t & 63;
    int lr = lane & 15, lu = lane >> 4;
    int qrow0 = g * NPG + qt * 64;

    // Q fragments for this wave's 16 rows (one-time strided load, ~16KB/block)
    f16x8 aq[4];
    {
        const f16* qp = (const f16*)qh + (size_t)(qrow0 + w * 16 + lr) * HD + lu * 8;
#pragma unroll
        for (int ks = 0; ks < 4; ++ks)
            aq[ks] = *(const f16x8*)(qp + ks * 32);
    }

    f32x4 p[8][4];       // [mt][ni], statically indexed
#pragma unroll
    for (int mt = 0; mt < 8; ++mt) {
        __syncthreads();                 // prev-tile consumers done
        {
            const float4* ks4 = (const float4*)(kh + (size_t)(g * NPG + mt * 64) * HD);
#pragma unroll
            for (int i = 0; i < 4; ++i) {
                int idx = t + 256 * i;   // 1024 x 16B = 64 rows x 16 chunks
                int row = idx >> 4, cq = idx & 15;
                *(float4*)&Kl[row][cq * 8] = ks4[row * 16 + cq];
            }
        }
        __syncthreads();
#pragma unroll
        for (int ni = 0; ni < 4; ++ni) {
            f32x4 acc = {0.f, 0.f, 0.f, 0.f};
#pragma unroll
            for (int ks = 0; ks < 4; ++ks) {
                f16x8 b = *(const f16x8*)&Kl[ni * 16 + lr][ks * 32 + lu * 8];
                acc = __builtin_amdgcn_mfma_f32_16x16x32_f16(aq[ks], b, acc, 0, 0, 0);
            }
            p[mt][ni] = acc;
        }
    }

    // row max per reg j (row = 16w + 4*lu + j), reduce over keys
    float mrow[4], linv[4];
#pragma unroll
    for (int j = 0; j < 4; ++j) {
        float m = p[0][0][j];
#pragma unroll
        for (int mt = 0; mt < 8; ++mt)
#pragma unroll
            for (int ni = 0; ni < 4; ++ni) m = fmaxf(m, p[mt][ni][j]);
        m = fmaxf(m, __shfl_xor(m, 1));
        m = fmaxf(m, __shfl_xor(m, 2));
        m = fmaxf(m, __shfl_xor(m, 4));
        m = fmaxf(m, __shfl_xor(m, 8));
        mrow[j] = m;
    }
    // exponentiate in place (scores scaled by 1/sqrt(H) at exp time)
#pragma unroll
    for (int mt = 0; mt < 8; ++mt)
#pragma unroll
        for (int ni = 0; ni < 4; ++ni)
#pragma unroll
            for (int j = 0; j < 4; ++j)
                p[mt][ni][j] = __expf((p[mt][ni][j] - mrow[j]) * RSQRT_H);
    // row sumexp -> 1/l
#pragma unroll
    for (int j = 0; j < 4; ++j) {
        float l = 0.f;
#pragma unroll
        for (int mt = 0; mt < 8; ++mt)
#pragma unroll
            for (int ni = 0; ni < 4; ++ni) l += p[mt][ni][j];
        l += __shfl_xor(l, 1);
        l += __shfl_xor(l, 2);
        l += __shfl_xor(l, 4);
        l += __shfl_xor(l, 8);
        linv[j] = 1.f / l;
    }
    // column sums of normalized attention -> per-wave slice (no atomics)
#pragma unroll
    for (int mt = 0; mt < 8; ++mt)
#pragma unroll
        for (int ni = 0; ni < 4; ++ni) {
            float pc = p[mt][ni][0] * linv[0] + p[mt][ni][1] * linv[1]
                     + p[mt][ni][2] * linv[2] + p[mt][ni][3] * linv[3];
            pc += __shfl_xor(pc, 16);
            pc += __shfl_xor(pc, 32);
            if (lu == 0) wlp[w][mt * 64 + ni * 16 + lr] = pc;
        }
    __syncthreads();
    float* wp = wpart + ((size_t)(g * 8 + qt)) * NPG;
    wp[t] = (wlp[0][t] + wlp[1][t] + wlp[2][t] + wlp[3][t]) * (1.f / NPG);
    wp[t + 256] = (wlp[0][t + 256] + wlp[1][t + 256] + wlp[2][t + 256]
                 + wlp[3][t + 256]) * (1.f / NPG);
}

// ---------------------------------------------------------------- pool + head
// u-partials: block (g,ch) sums 64 rows; w = sum of 8 qt slices. No atomics.
__global__ __launch_bounds__(128) void k_pool(
    const float* __restrict__ wpart, const float* __restrict__ h,
    float* __restrict__ upart)
{
    __shared__ float wloc[64];
    int b = blockIdx.x;
    int g = b >> 3, ch = b & 7;
    int t = threadIdx.x;
    if (t < 64) {
        float w = 0.f;
#pragma unroll
        for (int qt = 0; qt < 8; ++qt)
            w += wpart[((size_t)(g * 8 + qt)) * NPG + ch * 64 + t];
        wloc[t] = w;
    }
    __syncthreads();
    const float* hg = h + ((size_t)g * NPG + ch * 64) * HD;
    float u = 0.f;
#pragma unroll 4
    for (int m = 0; m < 64; ++m) u += wloc[m] * hg[m * HD + t];
    upart[(size_t)(ch * GG + g) * HD + t] = u;
}

__global__ __launch_bounds__(128) void k_head2(
    const float* __restrict__ upart,
    const float* __restrict__ Wv, const float* __restrict__ bv,
    const float* __restrict__ Wh1, const float* __restrict__ bh1,
    const float* __restrict__ Wh2, const float* __restrict__ bh2,
    float* __restrict__ out)
{
    __shared__ float ul[128];
    __shared__ float pl[128];
    __shared__ float r1l[64];
    int g = blockIdx.x, t = threadIdx.x;
    float ud = 0.f;
#pragma unroll
    for (int ch = 0; ch < 8; ++ch) ud += upart[(size_t)(ch * GG + g) * HD + t];
    ul[t] = ud;
    __syncthreads();
    float pv = bv[t];
    for (int d = 0; d < HD; ++d) pv += ul[d] * Wv[d * HD + t];
    pl[t] = pv;
    __syncthreads();
    if (t < 64) {
        float r1 = bh1[t];
        for (int d = 0; d < HD; ++d) r1 += pl[d] * Wh1[d * 64 + t];
        r1l[t] = fmaxf(r1, 0.f);
    }
    __syncthreads();
    if (t == 0) {
        float o = bh2[0];
        for (int j = 0; j < 64; ++j) o += r1l[j] * Wh2[j];
        out[g] = o;
    }
}

// ---------------------------------------------------------------- launch
extern "C" void kernel_launch(void* const* d_in, const int* in_sizes, int n_in,
                              void* d_out, int out_size, void* d_ws, size_t ws_size,
                              hipStream_t stream) {
    const float* x   = (const float*)d_in[0];
    const int* edge  = (const int*)d_in[1];
    // d_in[2] = batch (unused: batch = arange // 512 exactly)
    const float* W1  = (const float*)d_in[3];
    const float* b1  = (const float*)d_in[4];
    const float* W2  = (const float*)d_in[5];
    const float* b2  = (const float*)d_in[6];
    const float* Wq  = (const float*)d_in[7];
    const float* bq  = (const float*)d_in[8];
    const float* Wk  = (const float*)d_in[9];
    const float* bk  = (const float*)d_in[10];
    const float* Wv  = (const float*)d_in[11];
    const float* bv  = (const float*)d_in[12];
    const float* Wh1 = (const float*)d_in[13];
    const float* bh1 = (const float*)d_in[14];
    const float* Wh2 = (const float*)d_in[15];
    const float* bh2 = (const float*)d_in[16];
    float* out = (float*)d_out;

    int E = in_sizes[1] / 2;
    const int* src = edge;
    const int* dst = edge + E;

    // workspace layout (~51 MB):
    //  region1 [N*128 f32 = 16MB]: tmat fp16 (conv phase) -> qh fp16 | kh fp16
    //  region2 [N*128 f32]: hbuf
    //  region3 [N*128 f32]: ell int[N*64] early -> upart late
    //  wpart | cursor
    float* tbuf = (float*)d_ws;                      // region1
    float* hbuf = tbuf + (size_t)NN * HD;            // region2
    float* r3   = hbuf + (size_t)NN * HD;            // region3
    float* wpart = r3 + (size_t)NN * HD;             // [64*8][512]
    int* cursor = (int*)(wpart + GG * 8 * NPG);      // [N]
    __half* tmat = (__half*)tbuf;                    // [N][128] fp16 (8MB)
    __half* qh   = (__half*)tbuf;                    // [N][128] fp16 (after aggs)
    __half* kh   = qh + (size_t)NN * HD;             // [N][128] fp16 (second 8MB)
    int* ell    = (int*)r3;                          // [N][64], conv phase only
    float* upart = r3;                               // [8*64][128], after attn

    int eb = (E + 255) / 256;
    dim3 ggrid(NN / 64, 2);

    // graph structure (ELL, no scan, no init kernel)
    hipMemsetAsync(cursor, 0, NN * sizeof(int), stream);
    k_fill<<<eb, 256, 0, stream>>>(src, dst, cursor, ell, E);

    // conv1
    k_gemm_h<<<ggrid, 256, 0, stream>>>(x, W1, tmat, NN);
    k_agg<<<NN / 4, 256, 0, stream>>>(tmat, cursor, ell, b1, hbuf);
    // conv2
    k_gemm_h<<<ggrid, 256, 0, stream>>>(hbuf, W2, tmat, NN);
    k_agg<<<NN / 4, 256, 0, stream>>>(tmat, cursor, ell, b2, hbuf);
    // q + k fp16 row-major in one pass (tmat dead; qh/kh overlay region1)
    k_gemm_qk<<<ggrid, 256, 0, stream>>>(hbuf, Wq, bq, Wk, bk, qh, kh);
    // attention column weights via MFMA (per-qt slices, no atomics)
    k_attn<<<GG * 8, 256, 0, stream>>>(qh, kh, wpart);
    // pool partials + MLP head (upart overlays dead ell region)
    k_pool<<<GG * 8, 128, 0, stream>>>(wpart, hbuf, upart);
    k_head2<<<GG, 128, 0, stream>>>(upart, Wv, bv, Wh1, bh1, Wh2, bh2, out);
}

// Round 7
// 262.052 us; speedup vs baseline: 2.4024x; 1.1347x over previous
//
#include <hip/hip_runtime.h>
#include <hip/hip_fp16.h>
#include <hip/hip_bf16.h>

// Problem constants (fixed by the reference)
#define NN 32768      // nodes
#define GG 64         // graphs
#define NPG 512       // nodes per graph
#define HD 128        // feature/hidden width
#define MAXD 64       // ELL pad (mean degree 16, P(>64) ~ 1e-26)
#define RSQRT_H 0.08838834764831845f  // 1/sqrt(128)

typedef _Float16 f16;
typedef __attribute__((ext_vector_type(4))) _Float16 f16x4;
typedef __attribute__((ext_vector_type(8))) _Float16 f16x8;
typedef __attribute__((ext_vector_type(4))) float f32x4;

// ---------------------------------------------------------------- ELL build
__global__ void k_fill(const int* __restrict__ src, const int* __restrict__ dst,
                       int* __restrict__ cursor, int* __restrict__ ell, int E) {
    int e = blockIdx.x * 256 + threadIdx.x;
    if (e < E) {
        int d = dst[e];
        int slot = atomicAdd(&cursor[d], 1);
        if (slot < MAXD) ell[d * MAXD + slot] = src[e];
    }
}

// ---------------------------------------------------------------- weight prep
// WT[n][k] = (f16)W[k][n] for the 4 projection weights (MFMA B-operand needs
// k contiguous at fixed n). Tiny: 4 x 128 x 128.
__global__ void k_wprep(const float* __restrict__ W1, const float* __restrict__ W2,
                        const float* __restrict__ Wq, const float* __restrict__ Wk,
                        f16* __restrict__ wt) {
    const float* Ws[4] = {W1, W2, Wq, Wk};
    int k = blockIdx.x, wsel = blockIdx.y, n = threadIdx.x;
    float v = Ws[wsel][k * HD + n];              // coalesced read along n
    wt[(size_t)wsel * HD * HD + n * HD + k] = (f16)v;
}

// ---------------------------------------------------------------- MFMA GEMM
// [M,128]@[128,128] fp16 in / fp16 out. 64-row blocks, 4 waves, wave = 16
// rows x 128 cols = 8 ni-tiles x 4 ks = 32 mfma_f32_16x16x32_f16.
// Fragment index math identical to round-6 attn kernel (HW-verified):
//  A/B: lane l -> row/col l&15, k = (l>>4)*8 + j ; C/D: col = l&15,
//  row = (l>>4)*4 + reg. LDS pad 8 f16 -> 2-way-max bank aliasing (free).
template<int AF32, int BIAS>
__global__ __launch_bounds__(256) void k_mgemm(
    const void* __restrict__ Ain, const f16* __restrict__ WT,
    const float* __restrict__ bias, f16* __restrict__ out)
{
    __shared__ f16 Al[64][136];
    __shared__ f16 Wl[128][136];
    int t = threadIdx.x;
    int row0 = blockIdx.x * 64;
    int w = t >> 6, lane = t & 63, lr = lane & 15, lu = lane >> 4;

    if (AF32) {   // stage + cast fp32 A
        const float4* A32 = (const float4*)((const float*)Ain + (size_t)row0 * HD);
#pragma unroll
        for (int i = 0; i < 8; ++i) {
            int idx = t + 256 * i;        // 2048 = 64 rows x 32 chunks of 4 floats
            int r = idx >> 5, c4 = idx & 31;
            float4 v = A32[idx];
            f16x4 h = {(f16)v.x, (f16)v.y, (f16)v.z, (f16)v.w};
            *(f16x4*)&Al[r][c4 * 4] = h;
        }
    } else {      // stage fp16 A
        const float4* A16 = (const float4*)((const f16*)Ain + (size_t)row0 * HD);
#pragma unroll
        for (int i = 0; i < 4; ++i) {
            int idx = t + 256 * i;        // 1024 = 64 rows x 16 chunks of 8 f16
            int r = idx >> 4, cq = idx & 15;
            *(float4*)&Al[r][cq * 8] = A16[idx];
        }
    }
    const float4* W4 = (const float4*)WT;
#pragma unroll
    for (int i = 0; i < 8; ++i) {
        int idx = t + 256 * i;            // 2048 = 128 n-rows x 16 chunks
        int n = idx >> 4, cq = idx & 15;
        *(float4*)&Wl[n][cq * 8] = W4[idx];
    }
    __syncthreads();

    f16x8 aq[4];
#pragma unroll
    for (int ks = 0; ks < 4; ++ks)
        aq[ks] = *(const f16x8*)&Al[w * 16 + lr][ks * 32 + lu * 8];

    f32x4 acc[8];
#pragma unroll
    for (int ni = 0; ni < 8; ++ni) {
        f32x4 c = {0.f, 0.f, 0.f, 0.f};
#pragma unroll
        for (int ks = 0; ks < 4; ++ks) {
            f16x8 b = *(const f16x8*)&Wl[ni * 16 + lr][ks * 32 + lu * 8];
            c = __builtin_amdgcn_mfma_f32_16x16x32_f16(aq[ks], b, c, 0, 0, 0);
        }
        acc[ni] = c;
    }

    // epilogue: restage fp16 result in Al (dead) for coalesced float4 stores
    __syncthreads();
#pragma unroll
    for (int ni = 0; ni < 8; ++ni)
#pragma unroll
        for (int j = 0; j < 4; ++j) {
            float v = acc[ni][j];
            if (BIAS) v += bias[ni * 16 + lr];
            Al[w * 16 + lu * 4 + j][ni * 16 + lr] = (f16)v;
        }
    __syncthreads();
    float4* O4 = (float4*)(out + (size_t)row0 * HD);
#pragma unroll
    for (int i = 0; i < 4; ++i) {
        int idx = t + 256 * i;
        int r = idx >> 4, cq = idx & 15;
        O4[idx] = *(float4*)&Al[r][cq * 8];
    }
}

// ---------------------------------------------------------------- aggregation
// one 64-lane wave per node (4 nodes / 256-thread block); fp16 gather rows
// (256B coalesced per row), fp32 accumulate, fp16 out, dinv from cursor.
__global__ __launch_bounds__(256) void k_agg(
    const __half* __restrict__ tmat, const int* __restrict__ cursor,
    const int* __restrict__ ell, const float* __restrict__ bias,
    __half* __restrict__ hout)
{
    int t = threadIdx.x;
    int i = blockIdx.x * 4 + (t >> 6);   // node
    int lane = t & 63;                   // feature pair index
    int cnt = min(cursor[i], MAXD);
    float di = rsqrtf((float)(cnt + 1));
    float2 sv = __half22float2(((const __half2*)(tmat + (size_t)i * HD))[lane]);
    float acc0 = sv.x * (di * di);
    float acc1 = sv.y * (di * di);
    const int* row = ell + (size_t)i * MAXD;
    int e = 0;
    for (; e + 2 <= cnt; e += 2) {       // 2-edge ILP unroll
        int s0 = row[e], s1 = row[e + 1];
        float w0 = rsqrtf((float)(min(cursor[s0], MAXD) + 1)) * di;
        float w1 = rsqrtf((float)(min(cursor[s1], MAXD) + 1)) * di;
        float2 v0 = __half22float2(((const __half2*)(tmat + (size_t)s0 * HD))[lane]);
        float2 v1 = __half22float2(((const __half2*)(tmat + (size_t)s1 * HD))[lane]);
        acc0 += v0.x * w0 + v1.x * w1;
        acc1 += v0.y * w0 + v1.y * w1;
    }
    if (e < cnt) {
        int s0 = row[e];
        float w0 = rsqrtf((float)(min(cursor[s0], MAXD) + 1)) * di;
        float2 v0 = __half22float2(((const __half2*)(tmat + (size_t)s0 * HD))[lane]);
        acc0 += v0.x * w0;
        acc1 += v0.y * w0;
    }
    int f = lane * 2;
    __half2 o;
    o.x = __float2half(fmaxf(acc0 + bias[f], 0.f));
    o.y = __float2half(fmaxf(acc1 + bias[f + 1], 0.f));
    ((__half2*)(hout + (size_t)i * HD))[lane] = o;
}

// ---------------------------------------------------------------- attention
// MFMA QK^T (fp16 in, fp32 acc). Per block: 4 waves, wave w owns q-rows
// [16w,16w+16) of a 64-row q-tile; S strip (16x512) lives in 32 f32x4 accs.
__global__ __launch_bounds__(256, 2) void k_attn(
    const __half* __restrict__ qh,  // [N][128] fp16
    const __half* __restrict__ kh,  // [N][128] fp16
    float* __restrict__ wpart)      // [64*8][512]
{
    __shared__ f16 Kl[64][136];
    __shared__ float wlp[4][512];
    int t = threadIdx.x;
    int g = blockIdx.x >> 3;
    int qt = blockIdx.x & 7;
    int w = t >> 6, lane = t & 63;
    int lr = lane & 15, lu = lane >> 4;
    int qrow0 = g * NPG + qt * 64;

    f16x8 aq[4];
    {
        const f16* qp = (const f16*)qh + (size_t)(qrow0 + w * 16 + lr) * HD + lu * 8;
#pragma unroll
        for (int ks = 0; ks < 4; ++ks)
            aq[ks] = *(const f16x8*)(qp + ks * 32);
    }

    f32x4 p[8][4];       // [mt][ni], statically indexed
#pragma unroll
    for (int mt = 0; mt < 8; ++mt) {
        __syncthreads();                 // prev-tile consumers done
        {
            const float4* ks4 = (const float4*)(kh + (size_t)(g * NPG + mt * 64) * HD);
#pragma unroll
            for (int i = 0; i < 4; ++i) {
                int idx = t + 256 * i;   // 1024 x 16B = 64 rows x 16 chunks
                int row = idx >> 4, cq = idx & 15;
                *(float4*)&Kl[row][cq * 8] = ks4[row * 16 + cq];
            }
        }
        __syncthreads();
#pragma unroll
        for (int ni = 0; ni < 4; ++ni) {
            f32x4 acc = {0.f, 0.f, 0.f, 0.f};
#pragma unroll
            for (int ks = 0; ks < 4; ++ks) {
                f16x8 b = *(const f16x8*)&Kl[ni * 16 + lr][ks * 32 + lu * 8];
                acc = __builtin_amdgcn_mfma_f32_16x16x32_f16(aq[ks], b, acc, 0, 0, 0);
            }
            p[mt][ni] = acc;
        }
    }

    // row max per reg j (row = 16w + 4*lu + j)
    float mrow[4], linv[4];
#pragma unroll
    for (int j = 0; j < 4; ++j) {
        float m = p[0][0][j];
#pragma unroll
        for (int mt = 0; mt < 8; ++mt)
#pragma unroll
            for (int ni = 0; ni < 4; ++ni) m = fmaxf(m, p[mt][ni][j]);
        m = fmaxf(m, __shfl_xor(m, 1));
        m = fmaxf(m, __shfl_xor(m, 2));
        m = fmaxf(m, __shfl_xor(m, 4));
        m = fmaxf(m, __shfl_xor(m, 8));
        mrow[j] = m;
    }
#pragma unroll
    for (int mt = 0; mt < 8; ++mt)
#pragma unroll
        for (int ni = 0; ni < 4; ++ni)
#pragma unroll
            for (int j = 0; j < 4; ++j)
                p[mt][ni][j] = __expf((p[mt][ni][j] - mrow[j]) * RSQRT_H);
#pragma unroll
    for (int j = 0; j < 4; ++j) {
        float l = 0.f;
#pragma unroll
        for (int mt = 0; mt < 8; ++mt)
#pragma unroll
            for (int ni = 0; ni < 4; ++ni) l += p[mt][ni][j];
        l += __shfl_xor(l, 1);
        l += __shfl_xor(l, 2);
        l += __shfl_xor(l, 4);
        l += __shfl_xor(l, 8);
        linv[j] = 1.f / l;
    }
    // column sums of normalized attention -> per-wave slice (no atomics)
#pragma unroll
    for (int mt = 0; mt < 8; ++mt)
#pragma unroll
        for (int ni = 0; ni < 4; ++ni) {
            float pc = p[mt][ni][0] * linv[0] + p[mt][ni][1] * linv[1]
                     + p[mt][ni][2] * linv[2] + p[mt][ni][3] * linv[3];
            pc += __shfl_xor(pc, 16);
            pc += __shfl_xor(pc, 32);
            if (lu == 0) wlp[w][mt * 64 + ni * 16 + lr] = pc;
        }
    __syncthreads();
    float* wp = wpart + ((size_t)(g * 8 + qt)) * NPG;
    wp[t] = (wlp[0][t] + wlp[1][t] + wlp[2][t] + wlp[3][t]) * (1.f / NPG);
    wp[t + 256] = (wlp[0][t + 256] + wlp[1][t + 256] + wlp[2][t + 256]
                 + wlp[3][t + 256]) * (1.f / NPG);
}

// ---------------------------------------------------------------- pool + head
__global__ __launch_bounds__(128) void k_pool(
    const float* __restrict__ wpart, const __half* __restrict__ h,
    float* __restrict__ upart)
{
    __shared__ float wloc[64];
    int b = blockIdx.x;
    int g = b >> 3, ch = b & 7;
    int t = threadIdx.x;
    if (t < 64) {
        float w = 0.f;
#pragma unroll
        for (int qt = 0; qt < 8; ++qt)
            w += wpart[((size_t)(g * 8 + qt)) * NPG + ch * 64 + t];
        wloc[t] = w;
    }
    __syncthreads();
    const __half* hg = h + ((size_t)g * NPG + ch * 64) * HD;
    float u = 0.f;
#pragma unroll 4
    for (int m = 0; m < 64; ++m) u += wloc[m] * __half2float(hg[m * HD + t]);
    upart[(size_t)(ch * GG + g) * HD + t] = u;
}

__global__ __launch_bounds__(128) void k_head2(
    const float* __restrict__ upart,
    const float* __restrict__ Wv, const float* __restrict__ bv,
    const float* __restrict__ Wh1, const float* __restrict__ bh1,
    const float* __restrict__ Wh2, const float* __restrict__ bh2,
    float* __restrict__ out)
{
    __shared__ float ul[128];
    __shared__ float pl[128];
    __shared__ float r1l[64];
    int g = blockIdx.x, t = threadIdx.x;
    float ud = 0.f;
#pragma unroll
    for (int ch = 0; ch < 8; ++ch) ud += upart[(size_t)(ch * GG + g) * HD + t];
    ul[t] = ud;
    __syncthreads();
    float pv = bv[t];
    for (int d = 0; d < HD; ++d) pv += ul[d] * Wv[d * HD + t];
    pl[t] = pv;
    __syncthreads();
    if (t < 64) {
        float r1 = bh1[t];
        for (int d = 0; d < HD; ++d) r1 += pl[d] * Wh1[d * 64 + t];
        r1l[t] = fmaxf(r1, 0.f);
    }
    __syncthreads();
    if (t == 0) {
        float o = bh2[0];
        for (int j = 0; j < 64; ++j) o += r1l[j] * Wh2[j];
        out[g] = o;
    }
}

// ---------------------------------------------------------------- launch
extern "C" void kernel_launch(void* const* d_in, const int* in_sizes, int n_in,
                              void* d_out, int out_size, void* d_ws, size_t ws_size,
                              hipStream_t stream) {
    const float* x   = (const float*)d_in[0];
    const int* edge  = (const int*)d_in[1];
    // d_in[2] = batch (unused: batch = arange // 512 exactly)
    const float* W1  = (const float*)d_in[3];
    const float* b1  = (const float*)d_in[4];
    const float* W2  = (const float*)d_in[5];
    const float* b2  = (const float*)d_in[6];
    const float* Wq  = (const float*)d_in[7];
    const float* bq  = (const float*)d_in[8];
    const float* Wk  = (const float*)d_in[9];
    const float* bk  = (const float*)d_in[10];
    const float* Wv  = (const float*)d_in[11];
    const float* bv  = (const float*)d_in[12];
    const float* Wh1 = (const float*)d_in[13];
    const float* bh1 = (const float*)d_in[14];
    const float* Wh2 = (const float*)d_in[15];
    const float* bh2 = (const float*)d_in[16];
    float* out = (float*)d_out;

    int E = in_sizes[1] / 2;
    const int* src = edge;
    const int* dst = edge + E;

    // workspace layout (~51 MB):
    //  region1 [N*128 f32 = 16MB]: tmat fp16 (conv) -> qh fp16 | kh fp16
    //  region2 [N*128 f32]: hbuf fp16 (first 8MB)
    //  region3 [N*128 f32]: ell int[N*64] early -> upart late
    //  wpart | cursor | wtb (4x128x128 fp16 transposed weights)
    float* tbuf = (float*)d_ws;                      // region1
    float* hbr  = tbuf + (size_t)NN * HD;            // region2
    float* r3   = hbr + (size_t)NN * HD;             // region3
    float* wpart = r3 + (size_t)NN * HD;             // [64*8][512]
    int* cursor = (int*)(wpart + GG * 8 * NPG);      // [N]
    f16* wtb    = (f16*)(cursor + NN);               // [4][128][128] fp16
    __half* tmat = (__half*)tbuf;                    // [N][128] fp16 (8MB)
    __half* qh   = (__half*)tbuf;                    // [N][128] fp16 (after aggs)
    __half* kh   = qh + (size_t)NN * HD;             // [N][128] fp16 (second 8MB)
    __half* hbuf = (__half*)hbr;                     // [N][128] fp16
    int* ell    = (int*)r3;                          // [N][64], conv phase only
    float* upart = r3;                               // [8*64][128], after attn
    f16* W1T = wtb, *W2T = wtb + HD * HD, *WqT = wtb + 2 * HD * HD,
       * WkT = wtb + 3 * HD * HD;

    int eb = (E + 255) / 256;

    // graph structure + weight prep
    hipMemsetAsync(cursor, 0, NN * sizeof(int), stream);
    k_fill<<<eb, 256, 0, stream>>>(src, dst, cursor, ell, E);
    k_wprep<<<dim3(HD, 4), HD, 0, stream>>>(W1, W2, Wq, Wk, wtb);

    // conv1 (A = x fp32, cast in staging)
    k_mgemm<1, 0><<<NN / 64, 256, 0, stream>>>(x, W1T, nullptr, (f16*)tmat);
    k_agg<<<NN / 4, 256, 0, stream>>>(tmat, cursor, ell, b1, hbuf);
    // conv2
    k_mgemm<0, 0><<<NN / 64, 256, 0, stream>>>(hbuf, W2T, nullptr, (f16*)tmat);
    k_agg<<<NN / 4, 256, 0, stream>>>(tmat, cursor, ell, b2, hbuf);
    // q, k projections (ell dead after this point is NOT yet true: ell lives in
    // r3, only attn-independent; qh/kh overlay region1 where tmat is dead)
    k_mgemm<0, 1><<<NN / 64, 256, 0, stream>>>(hbuf, WqT, bq, (f16*)qh);
    k_mgemm<0, 1><<<NN / 64, 256, 0, stream>>>(hbuf, WkT, bk, (f16*)kh);
    // attention column weights via MFMA (per-qt slices, no atomics)
    k_attn<<<GG * 8, 256, 0, stream>>>(qh, kh, wpart);
    // pool partials + MLP head (upart overlays dead ell region)
    k_pool<<<GG * 8, 128, 0, stream>>>(wpart, hbuf, upart);
    k_head2<<<GG, 128, 0, stream>>>(upart, Wv, bv, Wh1, bh1, Wh2, bh2, out);
}